// Round 9
// baseline (1016.210 us; speedup 1.0000x reference)
//
#include <hip/hip_runtime.h>

#define NT 512

typedef __attribute__((ext_vector_type(8)))  short bh8;   // 8 bf16
typedef __attribute__((ext_vector_type(16))) float f16v;  // 32x32 acc
typedef __attribute__((ext_vector_type(4)))  float f4v;   // 16x16 acc
typedef __attribute__((ext_vector_type(2)))  float f2;    // packed f32 pair

// ---- d_ws layout (ushort units): pre-swizzled 64-lane x 16B fragment dumps.
#define FW_H    0      // sconv expanded-weight B-frags, 56 frags (28672)
#define FW_L    28672
#define W2A32_H 57344  // stage2 32x32 A-frags (isft), 9 frags (4608)
#define W2A32_L 61952
#define W3B_H   66560  // stage3 B-frags (scale*sft), 9 frags (4608)
#define W3B_L   71168  // end 75776 ush = 151552 B

// ---- LDS layout (ushort units) ----
// y B-frags at plane offset 0; s A-frags at +3072 for all layers EXCEPT
// layer 2 (needs 6144 -> overlaps y, protected by the mid-(b) barrier).
// For the disjoint layers the mid barrier is removed entirely.
#define SHo  0      // y/s frag region H plane (6144)
#define SLo  6144   // L plane
#define XHo  12288  // x planes [k][c] stride 72 (3456)
#define XLo  15744
#define NU   19200  // 38400 B -> 4 blocks/CU (512 thr: 32 waves/CU)

__device__ __forceinline__ unsigned short f2bf(float f) {  // RNE
  unsigned u = __float_as_uint(f);
  return (unsigned short)((u + 0x7fffu + ((u >> 16) & 1u)) >> 16);
}
__device__ __forceinline__ float bf2f(unsigned short h) {
  return __uint_as_float(((unsigned)h) << 16);
}
__device__ __forceinline__ int lidxf(int k) {  // degree band l/2 for coeff k
  return (k < 1) ? 0 : (k < 6) ? 1 : (k < 15) ? 2 : (k < 28) ? 3 : 4;
}
__device__ __forceinline__ float scale_from_j(int j) {  // sqrt(pi/(4j+1))
  float s = 1.7724539f;
  s = (j == 1) ? 0.79266548f : s;
  s = (j == 2) ? 0.59081795f : s;
  s = (j == 3) ? 0.49159026f : s;
  s = (j >= 4) ? 0.42988324f : s;
  return s;
}
__device__ __forceinline__ float rcp_from_j(int j) {  // 1/scale
  float s = 0.56418958f;
  s = (j == 1) ? 1.2615663f : s;
  s = (j == 2) ? 1.6925688f : s;
  s = (j == 3) ? 2.0342144f : s;
  s = (j >= 4) ? 2.3262120f : s;
  return s;
}
// packed split: hi = trunc-bf16 pair via v_perm; lo = trunc(v - bf2f(hi)) pair
__device__ __forceinline__ unsigned pk_hi(float a, float b) {
  return __builtin_amdgcn_perm(__float_as_uint(b), __float_as_uint(a), 0x07060302u);
}
__device__ __forceinline__ void split_store4(unsigned short* dh, unsigned short* dl,
                                             float v0, float v1, float v2, float v3) {
  f2 a01, a23, t01, t23;
  a01[0] = v0; a01[1] = v1; a23[0] = v2; a23[1] = v3;
  t01[0] = __uint_as_float(__float_as_uint(v0) & 0xffff0000u);
  t01[1] = __uint_as_float(__float_as_uint(v1) & 0xffff0000u);
  t23[0] = __uint_as_float(__float_as_uint(v2) & 0xffff0000u);
  t23[1] = __uint_as_float(__float_as_uint(v3) & 0xffff0000u);
  const f2 d01 = a01 - t01, d23 = a23 - t23;  // v_pk_add_f32
  *(uint2*)dh = make_uint2(pk_hi(v0, v1), pk_hi(v2, v3));
  *(uint2*)dl = make_uint2(pk_hi(d01[0], d01[1]), pk_hi(d23[0], d23[1]));
}

// ======================= pre-kernel: build fragment dumps =======================
__global__ void scnn_prep(const float* __restrict__ sft, const float* __restrict__ isft,
                          const float* __restrict__ w1, const float* __restrict__ w2,
                          const float* __restrict__ w3, const float* __restrict__ w4,
                          const float* __restrict__ w5, const float* __restrict__ w6,
                          unsigned short* __restrict__ wsu) {
  const int gid = blockIdx.x * NT + threadIdx.x;
  const int gstr = gridDim.x * NT;
  const float* wp[6] = {w1, w2, w3, w4, w5, w6};
  const int CIN[6] = {4, 16, 32, 64, 32, 16};
  const int COUT[6] = {16, 32, 64, 32, 16, 4};
  const int LG[6] = {3, 4, 5, 6, 5, 4};
  const int NST[6] = {2, 3, 5, 10, 5, 3};
  const int NTC[6] = {1, 2, 4, 2, 1, 1};
  const int FOFF[6] = {0, 2, 8, 28, 48, 53};
#pragma unroll
  for (int l = 0; l < 6; ++l) {
    const int cin = CIN[l], cout = COUT[l], lg = LG[l], cinP = 1 << lg;
    const int nst = NST[l];
    const int n = NTC[l] * nst * 512;
    const float* w = wp[l];
    const int base = FOFF[l] * 512;
    for (int i = gid; i < n; i += gstr) {
      const int fid = i >> 9, lane = (i >> 3) & 63, e = i & 7;
      const int nt = fid / nst, st = fid - nt * nst;
      const int o = nt * 16 + (lane & 15);
      const int s = st * 32 + (lane >> 4) * 8 + e;
      const int j = s >> lg, c = s & (cinP - 1);
      float v = 0.f;
      if (o < cout && j < 5 && c < cin) v = w[(o * cin + c) * 5 + j];
      const unsigned short h = f2bf(v);
      wsu[FW_H + base + i] = h;
      wsu[FW_L + base + i] = f2bf(v - bf2f(h));
    }
  }
  for (int i = gid; i < 9 * 512; i += gstr) {  // stage2 32x32 A-frags (isft)
    const int fid = i >> 9, lane = (i >> 3) & 63, e = i & 7;
    const int mt = fid / 3, ks = fid - mt * 3;
    const int p = mt * 32 + (lane & 31);
    const int k = ks * 16 + (lane >> 5) * 8 + e;
    const float v = (p < 90 && k < 45) ? isft[p * 45 + k] : 0.f;
    const unsigned short h = f2bf(v);
    wsu[W2A32_H + i] = h;
    wsu[W2A32_L + i] = f2bf(v - bf2f(h));
  }
  for (int i = gid; i < 9 * 512; i += gstr) {  // stage3 B-frags (scale*sft)
    const int fid = i >> 9, lane = (i >> 3) & 63, e = i & 7;
    const int ntK = fid / 3, sl = fid - ntK * 3;
    const int kk = ntK * 16 + (lane & 15);
    const int p = sl * 32 + (lane >> 4) * 8 + e;
    float v = 0.f;
    if (kk < 45 && p < 90) v = sft[kk * 90 + p] * scale_from_j(lidxf(kk));
    const unsigned short h = f2bf(v);
    wsu[W3B_H + i] = h;
    wsu[W3B_L + i] = f2bf(v - bf2f(h));
  }
}

// stage2 tile with preloaded ks=0 A-frag pair (loaded before the stage-a barrier).
__device__ __forceinline__ f16v s2tile_pre(const unsigned short* U,
                                           const unsigned short* fh, int nt, int lof,
                                           bh8 pah, bh8 pal) {
  f16v a;
#pragma unroll
  for (int e = 0; e < 16; ++e) a[e] = 0.f;
  const unsigned short* yb = U + SHo + nt * 3 * 512 + lof;
  {
    const bh8 bhv = *(const bh8*)&yb[0];
    const bh8 blv = *(const bh8*)&yb[SLo - SHo];
    a = __builtin_amdgcn_mfma_f32_32x32x16_bf16(pah, bhv, a, 0, 0, 0);
    a = __builtin_amdgcn_mfma_f32_32x32x16_bf16(pal, bhv, a, 0, 0, 0);
    a = __builtin_amdgcn_mfma_f32_32x32x16_bf16(pah, blv, a, 0, 0, 0);
  }
#pragma unroll
  for (int ks = 1; ks < 3; ++ks) {
    const bh8 ah = *(const bh8*)&fh[ks * 512];
    const bh8 al = *(const bh8*)&fh[(W2A32_L - W2A32_H) + ks * 512];
    const bh8 bhv = *(const bh8*)&yb[ks * 512];
    const bh8 blv = *(const bh8*)&yb[(SLo - SHo) + ks * 512];
    a = __builtin_amdgcn_mfma_f32_32x32x16_bf16(ah, bhv, a, 0, 0, 0);
    a = __builtin_amdgcn_mfma_f32_32x32x16_bf16(al, bhv, a, 0, 0, 0);
    a = __builtin_amdgcn_mfma_f32_32x32x16_bf16(ah, blv, a, 0, 0, 0);
  }
  return a;
}
// write s (ReLU'd) into stage-(d) A-frag layout at plane offset soff.
__device__ __forceinline__ void writes_s(unsigned short* U, f16v acc, int mt,
                                         int nt, int llo, int lhi, int soff) {
  const int so = soff + ((nt * 2 + (llo >> 4)) * 3 + mt) * 512 + (llo & 15) * 8 + lhi * 4;
#pragma unroll
  for (int g = 0; g < 4; ++g) {
    const int off = so + g * 128;
    split_store4(&U[SHo + off], &U[SLo + off],
                 fmaxf(acc[g * 4 + 0], 0.f), fmaxf(acc[g * 4 + 1], 0.f),
                 fmaxf(acc[g * 4 + 2], 0.f), fmaxf(acc[g * 4 + 3], 0.f));
  }
}

// ---- stage (a) tile, mt compile-time (r8 form, unchanged)
template <int layer, int mt>
__device__ __forceinline__ void atile(unsigned short* U,
                                      const unsigned short* __restrict__ wsu,
                                      int nt, int l15, int q4, int lof) {
  constexpr int lg   = (layer == 0) ? 3 : (layer == 1) ? 4 : (layer == 2) ? 5
                     : (layer == 3) ? 6 : (layer == 4) ? 5 : 4;
  constexpr int cinP = 1 << lg;
  constexpr int NSTc = (layer == 0) ? 2 : (layer == 1) ? 3 : (layer == 2) ? 5
                     : (layer == 3) ? 10 : (layer == 4) ? 5 : 3;
  constexpr int FOFFc= (layer == 0) ? 0 : (layer == 1) ? 2 : (layer == 2) ? 8
                     : (layer == 3) ? 28 : (layer == 4) ? 48 : 53;
  constexpr int hi5 = (5 * cinP + 31) >> 5;
  constexpr int hi4 = (4 * cinP + 31) >> 5;
  constexpr int lo3 = (3 * cinP) >> 5;
  constexpr int lo4 = cinP >> 3;
  constexpr int lo = (mt == 0) ? 0 : (mt == 1) ? lo3 : lo4;
  constexpr int hi = (mt == 0) ? hi4 : hi5;
  (void)cinP;

  const int k = mt * 16 + l15;
  const int jb = lidxf(k) << lg;
  const unsigned short* wfh = wsu + FW_H + (FOFFc + nt * NSTc) * 512 + lof;
  f4v a;
  a[0] = a[1] = a[2] = a[3] = 0.f;
#pragma unroll
  for (int st = lo; st < hi; ++st) {
    const int S = st * 32 + q4 * 8;
    const unsigned c0 = (unsigned)(S - jb);
    const unsigned cc = c0 < 64u ? c0 : 64u;  // OOB -> zero pad col
    const unsigned short* xp = &U[XHo + k * 72 + (int)cc];
    const bh8 xh = *(const bh8*)xp;
    const bh8 xl = *(const bh8*)(xp + (XLo - XHo));
    const bh8 wh = *(const bh8*)&wfh[st * 512];
    const bh8 wl = *(const bh8*)&wfh[(FW_L - FW_H) + st * 512];
    a = __builtin_amdgcn_mfma_f32_16x16x32_bf16(xh, wh, a, 0, 0, 0);
    a = __builtin_amdgcn_mfma_f32_16x16x32_bf16(xl, wh, a, 0, 0, 0);
    a = __builtin_amdgcn_mfma_f32_16x16x32_bf16(xh, wl, a, 0, 0, 0);
  }
  const int off = (((nt >> 1) * 3 + mt) << 9) +
                  ((q4 >> 1) * 32 + (nt & 1) * 16 + l15) * 8 + (q4 & 1) * 4;
  split_store4(&U[SHo + off], &U[SLo + off], a[0], a[1], a[2], a[3]);
}

// stage-d tile body given preloaded/loaded sl=0 B pair handled by caller.
__device__ __forceinline__ void d3tail(f4v& a, const unsigned short* U,
                                       const unsigned short* fb,
                                       const unsigned short* ab) {
#pragma unroll
  for (int sl = 1; sl < 3; ++sl) {
    const bh8 ah = *(const bh8*)&ab[sl * 512];
    const bh8 al = *(const bh8*)&ab[(SLo - SHo) + sl * 512];
    const bh8 bhv = *(const bh8*)&fb[sl * 512];
    const bh8 blv = *(const bh8*)&fb[(W3B_L - W3B_H) + sl * 512];
    a = __builtin_amdgcn_mfma_f32_16x16x32_bf16(ah, bhv, a, 0, 0, 0);
    a = __builtin_amdgcn_mfma_f32_16x16x32_bf16(al, bhv, a, 0, 0, 0);
    a = __builtin_amdgcn_mfma_f32_16x16x32_bf16(ah, blv, a, 0, 0, 0);
  }
}
__device__ __forceinline__ void dstore(unsigned short* U, f4v a, int ntK, int mtO,
                                       int l15, int q4, int layer_zero_mode) {
  const int kk = ntK * 16 + l15;
  const int oc = mtO * 16 + q4 * 4;
  split_store4(&U[XHo + kk * 72 + oc], &U[XLo + kk * 72 + oc],
               a[0], a[1], a[2], a[3]);
  if (layer_zero_mode == 1) {  // next layer cinP=32: cols 32-63 must be zero
    const uint2 z = make_uint2(0u, 0u);
    *(uint2*)&U[XHo + kk * 72 + oc + 32] = z;
    *(uint2*)&U[XLo + kk * 72 + oc + 32] = z;
  }
  if (layer_zero_mode == 2) {  // next layer cinP=16: cols 16-31 must be zero
    const uint2 z = make_uint2(0u, 0u);
    *(uint2*)&U[XHo + kk * 72 + oc + 16] = z;
    *(uint2*)&U[XLo + kk * 72 + oc + 16] = z;
  }
}

// ======================= per-layer body =======================
template <int layer>
__device__ __forceinline__ void layer_body(unsigned short* U,
                                           const unsigned short* __restrict__ wsu,
                                           int tid, int wv, int llo, int lhi,
                                           int l15, int q4, int lof) {
  constexpr int nt16 = (layer == 2) ? 4 : (layer == 1 || layer == 3) ? 2 : 1;
  constexpr int n32  = (layer == 2) ? 2 : 1;
  constexpr int soff = (layer == 2) ? 0 : 3072;  // disjoint s region unless L2
  constexpr int zmode = (layer == 3) ? 1 : (layer == 4) ? 2 : 0;

  // ---- (a) sconv via MFMA -> y B-frags
  {
    constexpr int T = 3 * nt16;
    for (int t = wv; t < T; t += 8) {
      const int mt = t % 3, nt = t / 3;
      if (mt == 0)      atile<layer, 0>(U, wsu, nt, l15, q4, lof);
      else if (mt == 1) atile<layer, 1>(U, wsu, nt, l15, q4, lof);
      else              atile<layer, 2>(U, wsu, nt, l15, q4, lof);
    }
  }
  // ---- preload stage-b ks=0 A-frag pair (global, no LDS dep) across barrier
  constexpr int T2 = 3 * n32;
  const bool hA = wv < T2;
  const unsigned short* fh = wsu + W2A32_H + (wv % 3) * 3 * 512 + lof;
  bh8 pah, pal;
  if (hA) {
    pah = *(const bh8*)&fh[0];
    pal = *(const bh8*)&fh[W2A32_L - W2A32_H];
  }
  __syncthreads();  // end of stage (a)

  // ---- (b)+(c) stage2 MFMA; mid barrier ONLY for layer 2 (y/s overlap)
  {
    f16v a0;
    if (hA) a0 = s2tile_pre(U, fh, wv / 3, lof, pah, pal);
    if constexpr (layer == 2) __syncthreads();
    if (hA) writes_s(U, a0, wv % 3, wv / 3, llo, lhi, soff);
  }
  // ---- preload stage-d sl=0 B-frag pair (global) across barrier
  constexpr int T3 = 3 * nt16;
  const bool hD = wv < T3;
  const unsigned short* fb0 = wsu + W3B_H + (wv % 3) * 3 * 512 + lof;
  bh8 pb, plb;
  if (hD) {
    pb = *(const bh8*)&fb0[0];
    plb = *(const bh8*)&fb0[W3B_L - W3B_H];
  }
  __syncthreads();  // end of stage (b)

  // ---- (d) stage3 MFMA: A = s frags (LDS), B = WS' frags (global)
  if (hD) {
    const int ntK = wv % 3, mtO = wv / 3;
    const unsigned short* ab = U + SHo + soff + mtO * 3 * 512 + lof;
    f4v a;
    a[0] = a[1] = a[2] = a[3] = 0.f;
    {
      const bh8 ah = *(const bh8*)&ab[0];
      const bh8 al = *(const bh8*)&ab[SLo - SHo];
      a = __builtin_amdgcn_mfma_f32_16x16x32_bf16(ah, pb, a, 0, 0, 0);
      a = __builtin_amdgcn_mfma_f32_16x16x32_bf16(al, pb, a, 0, 0, 0);
      a = __builtin_amdgcn_mfma_f32_16x16x32_bf16(ah, plb, a, 0, 0, 0);
    }
    d3tail(a, U, fb0, ab);
    dstore(U, a, ntK, mtO, l15, q4, zmode);
  }
  if constexpr (layer == 2) {  // second stage-d tile: t = wv+8 in [8,12)
    if (wv < 4) {
      const int t = wv + 8;
      const int ntK = t % 3, mtO = t / 3;
      const unsigned short* fb = wsu + W3B_H + ntK * 3 * 512 + lof;
      const unsigned short* ab = U + SHo + soff + mtO * 3 * 512 + lof;
      f4v a;
      a[0] = a[1] = a[2] = a[3] = 0.f;
      {
        const bh8 ah = *(const bh8*)&ab[0];
        const bh8 al = *(const bh8*)&ab[SLo - SHo];
        const bh8 bhv = *(const bh8*)&fb[0];
        const bh8 blv = *(const bh8*)&fb[W3B_L - W3B_H];
        a = __builtin_amdgcn_mfma_f32_16x16x32_bf16(ah, bhv, a, 0, 0, 0);
        a = __builtin_amdgcn_mfma_f32_16x16x32_bf16(al, bhv, a, 0, 0, 0);
        a = __builtin_amdgcn_mfma_f32_16x16x32_bf16(ah, blv, a, 0, 0, 0);
      }
      d3tail(a, U, fb, ab);
      dstore(U, a, ntK, mtO, l15, q4, zmode);
    }
  }
  __syncthreads();  // end of stage (d)
}

// ======================= main kernel =======================
__global__ __launch_bounds__(NT, 8)
void scnn_main(const float* __restrict__ xin, const unsigned short* __restrict__ wsu,
               float* __restrict__ out) {
  __shared__ __align__(16) unsigned short U[NU];
  const int tid = threadIdx.x, b = blockIdx.x;
  const int lane = tid & 63, wv = tid >> 6;
  const int llo = lane & 31, lhi = lane >> 5;
  const int l15 = lane & 15, q4 = lane >> 4;
  const int lof = lane << 3;

  // ---- zero-fill entire X region (both planes contiguous: 6912 ush = 1728 uint2)
  for (int i = tid; i < 1728; i += NT)
    ((uint2*)&U[XHo])[i] = make_uint2(0u, 0u);
  __syncthreads();
  // ---- stage initial X: [k][c] stride 72, live cols 0..3, scale-folded
  for (int i = tid; i < 180; i += NT) {
    const int c = i / 45, k = i - c * 45;
    const float v = xin[(size_t)b * 180 + i] * scale_from_j(lidxf(k));
    const unsigned u = __float_as_uint(v);
    const unsigned short h = (unsigned short)(u >> 16);
    U[XHo + k * 72 + c] = h;
    U[XLo + k * 72 + c] = f2bf(v - bf2f(h));
  }
  __syncthreads();

  layer_body<0>(U, wsu, tid, wv, llo, lhi, l15, q4, lof);
  layer_body<1>(U, wsu, tid, wv, llo, lhi, l15, q4, lof);
  layer_body<2>(U, wsu, tid, wv, llo, lhi, l15, q4, lof);
  layer_body<3>(U, wsu, tid, wv, llo, lhi, l15, q4, lof);
  layer_body<4>(U, wsu, tid, wv, llo, lhi, l15, q4, lof);
  layer_body<5>(U, wsu, tid, wv, llo, lhi, l15, q4, lof);

  // ---- epilogue: out[b][c][k] = (XH+XL)[k][c] * (1/scale[k])
  for (int i = tid; i < 180; i += NT) {
    const int c = i / 45, k = i - c * 45;
    const float v = bf2f(U[XHo + k * 72 + c]) + bf2f(U[XLo + k * 72 + c]);
    out[(size_t)b * 180 + i] = v * rcp_from_j(lidxf(k));
  }
}

extern "C" void kernel_launch(void* const* d_in, const int* in_sizes, int n_in,
                              void* d_out, int out_size, void* d_ws, size_t ws_size,
                              hipStream_t stream) {
  (void)n_in; (void)out_size; (void)ws_size;
  const float* x    = (const float*)d_in[0];
  const float* sft  = (const float*)d_in[1];
  const float* isft = (const float*)d_in[2];
  const float* w1   = (const float*)d_in[3];
  const float* w2   = (const float*)d_in[4];
  const float* w3   = (const float*)d_in[5];
  const float* w4   = (const float*)d_in[6];
  const float* w5   = (const float*)d_in[7];
  const float* w6   = (const float*)d_in[8];
  float* out = (float*)d_out;
  unsigned short* wsu = (unsigned short*)d_ws;  // uses 151552 B of scratch
  const int nb = in_sizes[0] / 180;             // 50000
  scnn_prep<<<64, NT, 0, stream>>>(sft, isft, w1, w2, w3, w4, w5, w6, wsu);
  scnn_main<<<nb, NT, 0, stream>>>(x, wsu, out);
}

// Round 12
// 1013.990 us; speedup vs baseline: 1.0022x; 1.0022x over previous
//
#include <hip/hip_runtime.h>

#define NT 512

typedef __attribute__((ext_vector_type(8)))  short bh8;   // 8 bf16
typedef __attribute__((ext_vector_type(16))) float f16v;  // 32x32 acc
typedef __attribute__((ext_vector_type(4)))  float f4v;   // 16x16 acc
typedef __attribute__((ext_vector_type(2)))  float f2;    // packed f32 pair

// ---- d_ws layout (ushort units): pre-swizzled 64-lane x 16B fragment dumps.
#define FW_H    0      // sconv expanded-weight B-frags, 56 frags (28672)
#define FW_L    28672
#define W2A32_H 57344  // stage2 32x32 A-frags (isft), 9 frags (4608)
#define W2A32_L 61952
#define W3B_H   66560  // stage3 B-frags (scale*sft), 9 frags (4608)
#define W3B_L   71168  // end 75776 ush = 151552 B

// ---- LDS layout (ushort units) ----
// y B-frags at plane offset 0; s A-frags at +3072 for all layers EXCEPT
// layer 2 (needs 6144 -> overlaps y, protected by the mid-(b) barrier).
#define SHo  0      // y/s frag region H plane (6144)
#define SLo  6144   // L plane
#define XHo  12288  // x planes [k][c] stride 72 (3456)
#define XLo  15744
#define NU   19200  // 38400 B -> 4 blocks/CU (512 thr: 32 waves/CU)

__device__ __forceinline__ unsigned short f2bf(float f) {  // RNE
  unsigned u = __float_as_uint(f);
  return (unsigned short)((u + 0x7fffu + ((u >> 16) & 1u)) >> 16);
}
__device__ __forceinline__ float bf2f(unsigned short h) {
  return __uint_as_float(((unsigned)h) << 16);
}
__device__ __forceinline__ int lidxf(int k) {  // degree band l/2 for coeff k
  return (k < 1) ? 0 : (k < 6) ? 1 : (k < 15) ? 2 : (k < 28) ? 3 : 4;
}
__device__ __forceinline__ float scale_from_j(int j) {  // sqrt(pi/(4j+1))
  float s = 1.7724539f;
  s = (j == 1) ? 0.79266548f : s;
  s = (j == 2) ? 0.59081795f : s;
  s = (j == 3) ? 0.49159026f : s;
  s = (j >= 4) ? 0.42988324f : s;
  return s;
}
__device__ __forceinline__ float rcp_from_j(int j) {  // 1/scale
  float s = 0.56418958f;
  s = (j == 1) ? 1.2615663f : s;
  s = (j == 2) ? 1.6925688f : s;
  s = (j == 3) ? 2.0342144f : s;
  s = (j >= 4) ? 2.3262120f : s;
  return s;
}
// packed split: hi = trunc-bf16 pair via v_perm; lo = trunc(v - bf2f(hi)) pair
__device__ __forceinline__ unsigned pk_hi(float a, float b) {
  return __builtin_amdgcn_perm(__float_as_uint(b), __float_as_uint(a), 0x07060302u);
}
__device__ __forceinline__ void split_store4(unsigned short* dh, unsigned short* dl,
                                             float v0, float v1, float v2, float v3) {
  f2 a01, a23, t01, t23;
  a01[0] = v0; a01[1] = v1; a23[0] = v2; a23[1] = v3;
  t01[0] = __uint_as_float(__float_as_uint(v0) & 0xffff0000u);
  t01[1] = __uint_as_float(__float_as_uint(v1) & 0xffff0000u);
  t23[0] = __uint_as_float(__float_as_uint(v2) & 0xffff0000u);
  t23[1] = __uint_as_float(__float_as_uint(v3) & 0xffff0000u);
  const f2 d01 = a01 - t01, d23 = a23 - t23;  // v_pk_add_f32
  *(uint2*)dh = make_uint2(pk_hi(v0, v1), pk_hi(v2, v3));
  *(uint2*)dl = make_uint2(pk_hi(d01[0], d01[1]), pk_hi(d23[0], d23[1]));
}

// ======================= pre-kernel: build fragment dumps =======================
__global__ void scnn_prep(const float* __restrict__ sft, const float* __restrict__ isft,
                          const float* __restrict__ w1, const float* __restrict__ w2,
                          const float* __restrict__ w3, const float* __restrict__ w4,
                          const float* __restrict__ w5, const float* __restrict__ w6,
                          unsigned short* __restrict__ wsu) {
  const int gid = blockIdx.x * NT + threadIdx.x;
  const int gstr = gridDim.x * NT;
  const float* wp[6] = {w1, w2, w3, w4, w5, w6};
  const int CIN[6] = {4, 16, 32, 64, 32, 16};
  const int COUT[6] = {16, 32, 64, 32, 16, 4};
  const int LG[6] = {3, 4, 5, 6, 5, 4};
  const int NST[6] = {2, 3, 5, 10, 5, 3};
  const int NTC[6] = {1, 2, 4, 2, 1, 1};
  const int FOFF[6] = {0, 2, 8, 28, 48, 53};
#pragma unroll
  for (int l = 0; l < 6; ++l) {
    const int cin = CIN[l], cout = COUT[l], lg = LG[l], cinP = 1 << lg;
    const int nst = NST[l];
    const int n = NTC[l] * nst * 512;
    const float* w = wp[l];
    const int base = FOFF[l] * 512;
    for (int i = gid; i < n; i += gstr) {
      const int fid = i >> 9, lane = (i >> 3) & 63, e = i & 7;
      const int nt = fid / nst, st = fid - nt * nst;
      const int o = nt * 16 + (lane & 15);
      const int s = st * 32 + (lane >> 4) * 8 + e;
      const int j = s >> lg, c = s & (cinP - 1);
      float v = 0.f;
      if (o < cout && j < 5 && c < cin) v = w[(o * cin + c) * 5 + j];
      const unsigned short h = f2bf(v);
      wsu[FW_H + base + i] = h;
      wsu[FW_L + base + i] = f2bf(v - bf2f(h));
    }
  }
  for (int i = gid; i < 9 * 512; i += gstr) {  // stage2 32x32 A-frags (isft)
    const int fid = i >> 9, lane = (i >> 3) & 63, e = i & 7;
    const int mt = fid / 3, ks = fid - mt * 3;
    const int p = mt * 32 + (lane & 31);
    const int k = ks * 16 + (lane >> 5) * 8 + e;
    const float v = (p < 90 && k < 45) ? isft[p * 45 + k] : 0.f;
    const unsigned short h = f2bf(v);
    wsu[W2A32_H + i] = h;
    wsu[W2A32_L + i] = f2bf(v - bf2f(h));
  }
  for (int i = gid; i < 9 * 512; i += gstr) {  // stage3 B-frags (scale*sft)
    const int fid = i >> 9, lane = (i >> 3) & 63, e = i & 7;
    const int ntK = fid / 3, sl = fid - ntK * 3;
    const int kk = ntK * 16 + (lane & 15);
    const int p = sl * 32 + (lane >> 4) * 8 + e;
    float v = 0.f;
    if (kk < 45 && p < 90) v = sft[kk * 90 + p] * scale_from_j(lidxf(kk));
    const unsigned short h = f2bf(v);
    wsu[W3B_H + i] = h;
    wsu[W3B_L + i] = f2bf(v - bf2f(h));
  }
}

// stage2 tile with preloaded ks=0 A-frag pair (loaded before the stage-a barrier).
__device__ __forceinline__ f16v s2tile_pre(const unsigned short* U,
                                           const unsigned short* fh, int nt, int lof,
                                           bh8 pah, bh8 pal) {
  f16v a;
#pragma unroll
  for (int e = 0; e < 16; ++e) a[e] = 0.f;
  const unsigned short* yb = U + SHo + nt * 3 * 512 + lof;
  {
    const bh8 bhv = *(const bh8*)&yb[0];
    const bh8 blv = *(const bh8*)&yb[SLo - SHo];
    a = __builtin_amdgcn_mfma_f32_32x32x16_bf16(pah, bhv, a, 0, 0, 0);
    a = __builtin_amdgcn_mfma_f32_32x32x16_bf16(pal, bhv, a, 0, 0, 0);
    a = __builtin_amdgcn_mfma_f32_32x32x16_bf16(pah, blv, a, 0, 0, 0);
  }
#pragma unroll
  for (int ks = 1; ks < 3; ++ks) {
    const bh8 ah = *(const bh8*)&fh[ks * 512];
    const bh8 al = *(const bh8*)&fh[(W2A32_L - W2A32_H) + ks * 512];
    const bh8 bhv = *(const bh8*)&yb[ks * 512];
    const bh8 blv = *(const bh8*)&yb[(SLo - SHo) + ks * 512];
    a = __builtin_amdgcn_mfma_f32_32x32x16_bf16(ah, bhv, a, 0, 0, 0);
    a = __builtin_amdgcn_mfma_f32_32x32x16_bf16(al, bhv, a, 0, 0, 0);
    a = __builtin_amdgcn_mfma_f32_32x32x16_bf16(ah, blv, a, 0, 0, 0);
  }
  return a;
}
// write s (ReLU'd) into stage-(d) A-frag layout at plane offset soff.
__device__ __forceinline__ void writes_s(unsigned short* U, f16v acc, int mt,
                                         int nt, int llo, int lhi, int soff) {
  const int so = soff + ((nt * 2 + (llo >> 4)) * 3 + mt) * 512 + (llo & 15) * 8 + lhi * 4;
#pragma unroll
  for (int g = 0; g < 4; ++g) {
    const int off = so + g * 128;
    split_store4(&U[SHo + off], &U[SLo + off],
                 fmaxf(acc[g * 4 + 0], 0.f), fmaxf(acc[g * 4 + 1], 0.f),
                 fmaxf(acc[g * 4 + 2], 0.f), fmaxf(acc[g * 4 + 3], 0.f));
  }
}

// ---- stage (a) tile, mt compile-time (r8 form, unchanged)
template <int layer, int mt>
__device__ __forceinline__ void atile(unsigned short* U,
                                      const unsigned short* __restrict__ wsu,
                                      int nt, int l15, int q4, int lof) {
  constexpr int lg   = (layer == 0) ? 3 : (layer == 1) ? 4 : (layer == 2) ? 5
                     : (layer == 3) ? 6 : (layer == 4) ? 5 : 4;
  constexpr int cinP = 1 << lg;
  constexpr int NSTc = (layer == 0) ? 2 : (layer == 1) ? 3 : (layer == 2) ? 5
                     : (layer == 3) ? 10 : (layer == 4) ? 5 : 3;
  constexpr int FOFFc= (layer == 0) ? 0 : (layer == 1) ? 2 : (layer == 2) ? 8
                     : (layer == 3) ? 28 : (layer == 4) ? 48 : 53;
  constexpr int hi5 = (5 * cinP + 31) >> 5;
  constexpr int hi4 = (4 * cinP + 31) >> 5;
  constexpr int lo3 = (3 * cinP) >> 5;
  constexpr int lo4 = cinP >> 3;
  constexpr int lo = (mt == 0) ? 0 : (mt == 1) ? lo3 : lo4;
  constexpr int hi = (mt == 0) ? hi4 : hi5;
  (void)cinP;

  const int k = mt * 16 + l15;
  const int jb = lidxf(k) << lg;
  const unsigned short* wfh = wsu + FW_H + (FOFFc + nt * NSTc) * 512 + lof;
  f4v a;
  a[0] = a[1] = a[2] = a[3] = 0.f;
#pragma unroll
  for (int st = lo; st < hi; ++st) {
    const int S = st * 32 + q4 * 8;
    const unsigned c0 = (unsigned)(S - jb);
    const unsigned cc = c0 < 64u ? c0 : 64u;  // OOB -> zero pad col
    const unsigned short* xp = &U[XHo + k * 72 + (int)cc];
    const bh8 xh = *(const bh8*)xp;
    const bh8 xl = *(const bh8*)(xp + (XLo - XHo));
    const bh8 wh = *(const bh8*)&wfh[st * 512];
    const bh8 wl = *(const bh8*)&wfh[(FW_L - FW_H) + st * 512];
    a = __builtin_amdgcn_mfma_f32_16x16x32_bf16(xh, wh, a, 0, 0, 0);
    a = __builtin_amdgcn_mfma_f32_16x16x32_bf16(xl, wh, a, 0, 0, 0);
    a = __builtin_amdgcn_mfma_f32_16x16x32_bf16(xh, wl, a, 0, 0, 0);
  }
  const int off = (((nt >> 1) * 3 + mt) << 9) +
                  ((q4 >> 1) * 32 + (nt & 1) * 16 + l15) * 8 + (q4 & 1) * 4;
  split_store4(&U[SHo + off], &U[SLo + off], a[0], a[1], a[2], a[3]);
}

__device__ __forceinline__ void dstore(unsigned short* U, f4v a, int ntK, int mtO,
                                       int l15, int q4, int layer_zero_mode) {
  const int kk = ntK * 16 + l15;
  const int oc = mtO * 16 + q4 * 4;
  split_store4(&U[XHo + kk * 72 + oc], &U[XLo + kk * 72 + oc],
               a[0], a[1], a[2], a[3]);
  if (layer_zero_mode == 1) {  // next layer cinP=32: cols 32-63 must be zero
    const uint2 z = make_uint2(0u, 0u);
    *(uint2*)&U[XHo + kk * 72 + oc + 32] = z;
    *(uint2*)&U[XLo + kk * 72 + oc + 32] = z;
  }
  if (layer_zero_mode == 2) {  // next layer cinP=16: cols 16-31 must be zero
    const uint2 z = make_uint2(0u, 0u);
    *(uint2*)&U[XHo + kk * 72 + oc + 16] = z;
    *(uint2*)&U[XLo + kk * 72 + oc + 16] = z;
  }
}

// ======================= per-layer body =======================
template <int layer>
__device__ __forceinline__ void layer_body(unsigned short* U,
                                           const unsigned short* __restrict__ wsu,
                                           int tid, int wv, int llo, int lhi,
                                           int l15, int q4, int lof) {
  constexpr int nt16 = (layer == 2) ? 4 : (layer == 1 || layer == 3) ? 2 : 1;
  constexpr int n32  = (layer == 2) ? 2 : 1;
  constexpr int soff = (layer == 2) ? 0 : 3072;  // disjoint s region unless L2
  constexpr int zmode = (layer == 3) ? 1 : (layer == 4) ? 2 : 0;

  // ---- (a) sconv via MFMA -> y B-frags
  {
    constexpr int T = 3 * nt16;
    for (int t = wv; t < T; t += 8) {
      const int mt = t % 3, nt = t / 3;
      if (mt == 0)      atile<layer, 0>(U, wsu, nt, l15, q4, lof);
      else if (mt == 1) atile<layer, 1>(U, wsu, nt, l15, q4, lof);
      else              atile<layer, 2>(U, wsu, nt, l15, q4, lof);
    }
  }
  // ---- preload stage-b ks=0 A-frag pair (global, no LDS dep) across barrier
  constexpr int T2 = 3 * n32;
  const bool hA = wv < T2;
  const unsigned short* fh = wsu + W2A32_H + (wv % 3) * 3 * 512 + lof;
  bh8 pah, pal;
  if (hA) {
    pah = *(const bh8*)&fh[0];
    pal = *(const bh8*)&fh[W2A32_L - W2A32_H];
  }
  __syncthreads();  // end of stage (a)

  // ---- (b)+(c) stage2 MFMA; mid barrier ONLY for layer 2 (y/s overlap)
  {
    f16v a0;
    if (hA) a0 = s2tile_pre(U, fh, wv / 3, lof, pah, pal);
    if constexpr (layer == 2) __syncthreads();
    if (hA) writes_s(U, a0, wv % 3, wv / 3, llo, lhi, soff);
  }
  // ---- preload stage-d sl=0 B-frag pair for this group's first ntK
  const int grp = wv >> 2, mtO = wv & 3;
  const bool hD = mtO < nt16;
  const int ntKa = (grp == 0) ? 0 : 2;
  const unsigned short* fba = wsu + W3B_H + ntKa * 3 * 512 + lof;
  bh8 pb, plb;
  if (hD) {
    pb = *(const bh8*)&fba[0];
    plb = *(const bh8*)&fba[W3B_L - W3B_H];
  }
  __syncthreads();  // end of stage (b)

  // ---- (d) stage3 MFMA, shared s reads: grp0 waves (0-3) own ntK{0,1} with
  //      two accumulators and ONE ah/al read per sl; grp1 waves (4-7) own ntK{2}.
  if (hD) {
    const unsigned short* ab = U + SHo + soff + mtO * 3 * 512 + lof;
    if (grp == 0) {
      const unsigned short* fbb = wsu + W3B_H + 3 * 512 + lof;  // ntK=1
      f4v a0, a1;
      a0[0] = a0[1] = a0[2] = a0[3] = 0.f;
      a1[0] = a1[1] = a1[2] = a1[3] = 0.f;
#pragma unroll
      for (int sl = 0; sl < 3; ++sl) {
        const bh8 ah = *(const bh8*)&ab[sl * 512];
        const bh8 al = *(const bh8*)&ab[(SLo - SHo) + sl * 512];
        bh8 b0h, b0l;
        if (sl == 0) { b0h = pb; b0l = plb; }
        else {
          b0h = *(const bh8*)&fba[sl * 512];
          b0l = *(const bh8*)&fba[(W3B_L - W3B_H) + sl * 512];
        }
        const bh8 b1h = *(const bh8*)&fbb[sl * 512];
        const bh8 b1l = *(const bh8*)&fbb[(W3B_L - W3B_H) + sl * 512];
        a0 = __builtin_amdgcn_mfma_f32_16x16x32_bf16(ah, b0h, a0, 0, 0, 0);
        a0 = __builtin_amdgcn_mfma_f32_16x16x32_bf16(al, b0h, a0, 0, 0, 0);
        a0 = __builtin_amdgcn_mfma_f32_16x16x32_bf16(ah, b0l, a0, 0, 0, 0);
        a1 = __builtin_amdgcn_mfma_f32_16x16x32_bf16(ah, b1h, a1, 0, 0, 0);
        a1 = __builtin_amdgcn_mfma_f32_16x16x32_bf16(al, b1h, a1, 0, 0, 0);
        a1 = __builtin_amdgcn_mfma_f32_16x16x32_bf16(ah, b1l, a1, 0, 0, 0);
      }
      dstore(U, a0, 0, mtO, l15, q4, zmode);
      dstore(U, a1, 1, mtO, l15, q4, zmode);
    } else {
      f4v a;
      a[0] = a[1] = a[2] = a[3] = 0.f;
#pragma unroll
      for (int sl = 0; sl < 3; ++sl) {
        const bh8 ah = *(const bh8*)&ab[sl * 512];
        const bh8 al = *(const bh8*)&ab[(SLo - SHo) + sl * 512];
        bh8 bh_, bl_;
        if (sl == 0) { bh_ = pb; bl_ = plb; }
        else {
          bh_ = *(const bh8*)&fba[sl * 512];
          bl_ = *(const bh8*)&fba[(W3B_L - W3B_H) + sl * 512];
        }
        a = __builtin_amdgcn_mfma_f32_16x16x32_bf16(ah, bh_, a, 0, 0, 0);
        a = __builtin_amdgcn_mfma_f32_16x16x32_bf16(al, bh_, a, 0, 0, 0);
        a = __builtin_amdgcn_mfma_f32_16x16x32_bf16(ah, bl_, a, 0, 0, 0);
      }
      dstore(U, a, 2, mtO, l15, q4, zmode);
    }
  }
  __syncthreads();  // end of stage (d)
}

// ======================= main kernel =======================
__global__ __launch_bounds__(NT, 8)
void scnn_main(const float* __restrict__ xin, const unsigned short* __restrict__ wsu,
               float* __restrict__ out) {
  __shared__ __align__(16) unsigned short U[NU];
  const int tid = threadIdx.x, b = blockIdx.x;
  const int lane = tid & 63, wv = tid >> 6;
  const int llo = lane & 31, lhi = lane >> 5;
  const int l15 = lane & 15, q4 = lane >> 4;
  const int lof = lane << 3;

  // ---- zero-fill entire X region (both planes contiguous: 6912 ush = 1728 uint2)
  for (int i = tid; i < 1728; i += NT)
    ((uint2*)&U[XHo])[i] = make_uint2(0u, 0u);
  __syncthreads();
  // ---- stage initial X: [k][c] stride 72, live cols 0..3, scale-folded
  for (int i = tid; i < 180; i += NT) {
    const int c = i / 45, k = i - c * 45;
    const float v = xin[(size_t)b * 180 + i] * scale_from_j(lidxf(k));
    const unsigned u = __float_as_uint(v);
    const unsigned short h = (unsigned short)(u >> 16);
    U[XHo + k * 72 + c] = h;
    U[XLo + k * 72 + c] = f2bf(v - bf2f(h));
  }
  __syncthreads();

  layer_body<0>(U, wsu, tid, wv, llo, lhi, l15, q4, lof);
  layer_body<1>(U, wsu, tid, wv, llo, lhi, l15, q4, lof);
  layer_body<2>(U, wsu, tid, wv, llo, lhi, l15, q4, lof);
  layer_body<3>(U, wsu, tid, wv, llo, lhi, l15, q4, lof);
  layer_body<4>(U, wsu, tid, wv, llo, lhi, l15, q4, lof);
  layer_body<5>(U, wsu, tid, wv, llo, lhi, l15, q4, lof);

  // ---- epilogue: out[b][c][k] = (XH+XL)[k][c] * (1/scale[k])
  for (int i = tid; i < 180; i += NT) {
    const int c = i / 45, k = i - c * 45;
    const float v = bf2f(U[XHo + k * 72 + c]) + bf2f(U[XLo + k * 72 + c]);
    out[(size_t)b * 180 + i] = v * rcp_from_j(lidxf(k));
  }
}

extern "C" void kernel_launch(void* const* d_in, const int* in_sizes, int n_in,
                              void* d_out, int out_size, void* d_ws, size_t ws_size,
                              hipStream_t stream) {
  (void)n_in; (void)out_size; (void)ws_size;
  const float* x    = (const float*)d_in[0];
  const float* sft  = (const float*)d_in[1];
  const float* isft = (const float*)d_in[2];
  const float* w1   = (const float*)d_in[3];
  const float* w2   = (const float*)d_in[4];
  const float* w3   = (const float*)d_in[5];
  const float* w4   = (const float*)d_in[6];
  const float* w5   = (const float*)d_in[7];
  const float* w6   = (const float*)d_in[8];
  float* out = (float*)d_out;
  unsigned short* wsu = (unsigned short*)d_ws;  // uses 151552 B of scratch
  const int nb = in_sizes[0] / 180;             // 50000
  scnn_prep<<<64, NT, 0, stream>>>(sft, isft, w1, w2, w3, w4, w5, w6, wsu);
  scnn_main<<<nb, NT, 0, stream>>>(x, wsu, out);
}

// Round 13
// 798.636 us; speedup vs baseline: 1.2724x; 1.2697x over previous
//
#include <hip/hip_runtime.h>

#define NT 512

typedef __attribute__((ext_vector_type(8)))  short bh8;   // 8 bf16
typedef __attribute__((ext_vector_type(16))) float f16v;  // 32x32 acc
typedef __attribute__((ext_vector_type(4)))  float f4v;   // 16x16 acc
typedef __attribute__((ext_vector_type(2)))  float f2;    // packed f32 pair

// ---- d_ws layout (ushort units): pre-swizzled 64-lane x 16B fragment dumps.
#define FW_H    0      // sconv expanded-weight B-frags, 56 frags (28672)
#define FW_L    28672
#define W2A32_H 57344  // stage2 32x32 A-frags (isft), 9 frags (4608)
#define W2A32_L 61952
#define W3B_H   66560  // stage3 B-frags (scale*sft), 9 frags (4608)
#define W3B_L   71168  // end 75776 ush = 151552 B

// ---- LDS layout (ushort units) ----
// y B-frags at plane offset 0; s A-frags at +3072 for all layers EXCEPT
// layer 2 (needs 6144 -> overlaps y, protected by the mid-(b) barrier).
#define SHo  0      // y/s frag region H plane (6144)
#define SLo  6144   // L plane
#define XHo  12288  // x planes [k][c] stride 72 (3456)
#define XLo  15744
#define NU   19200  // 38400 B -> 4 blocks/CU (512 thr: 32 waves/CU)

__device__ __forceinline__ unsigned short f2bf(float f) {  // RNE
  unsigned u = __float_as_uint(f);
  return (unsigned short)((u + 0x7fffu + ((u >> 16) & 1u)) >> 16);
}
__device__ __forceinline__ float bf2f(unsigned short h) {
  return __uint_as_float(((unsigned)h) << 16);
}
__device__ __forceinline__ int lidxf(int k) {  // degree band l/2 for coeff k
  return (k < 1) ? 0 : (k < 6) ? 1 : (k < 15) ? 2 : (k < 28) ? 3 : 4;
}
__device__ __forceinline__ float scale_from_j(int j) {  // sqrt(pi/(4j+1))
  float s = 1.7724539f;
  s = (j == 1) ? 0.79266548f : s;
  s = (j == 2) ? 0.59081795f : s;
  s = (j == 3) ? 0.49159026f : s;
  s = (j >= 4) ? 0.42988324f : s;
  return s;
}
__device__ __forceinline__ float rcp_from_j(int j) {  // 1/scale
  float s = 0.56418958f;
  s = (j == 1) ? 1.2615663f : s;
  s = (j == 2) ? 1.6925688f : s;
  s = (j == 3) ? 2.0342144f : s;
  s = (j >= 4) ? 2.3262120f : s;
  return s;
}
// packed split: hi = trunc-bf16 pair via v_perm; lo = trunc(v - bf2f(hi)) pair
__device__ __forceinline__ unsigned pk_hi(float a, float b) {
  return __builtin_amdgcn_perm(__float_as_uint(b), __float_as_uint(a), 0x07060302u);
}
__device__ __forceinline__ void split_store4(unsigned short* dh, unsigned short* dl,
                                             float v0, float v1, float v2, float v3) {
  f2 a01, a23, t01, t23;
  a01[0] = v0; a01[1] = v1; a23[0] = v2; a23[1] = v3;
  t01[0] = __uint_as_float(__float_as_uint(v0) & 0xffff0000u);
  t01[1] = __uint_as_float(__float_as_uint(v1) & 0xffff0000u);
  t23[0] = __uint_as_float(__float_as_uint(v2) & 0xffff0000u);
  t23[1] = __uint_as_float(__float_as_uint(v3) & 0xffff0000u);
  const f2 d01 = a01 - t01, d23 = a23 - t23;  // v_pk_add_f32
  *(uint2*)dh = make_uint2(pk_hi(v0, v1), pk_hi(v2, v3));
  *(uint2*)dl = make_uint2(pk_hi(d01[0], d01[1]), pk_hi(d23[0], d23[1]));
}

// ======================= pre-kernel: build fragment dumps =======================
__global__ void scnn_prep(const float* __restrict__ sft, const float* __restrict__ isft,
                          const float* __restrict__ w1, const float* __restrict__ w2,
                          const float* __restrict__ w3, const float* __restrict__ w4,
                          const float* __restrict__ w5, const float* __restrict__ w6,
                          unsigned short* __restrict__ wsu) {
  const int gid = blockIdx.x * NT + threadIdx.x;
  const int gstr = gridDim.x * NT;
  const float* wp[6] = {w1, w2, w3, w4, w5, w6};
  const int CIN[6] = {4, 16, 32, 64, 32, 16};
  const int COUT[6] = {16, 32, 64, 32, 16, 4};
  const int LG[6] = {3, 4, 5, 6, 5, 4};
  const int NST[6] = {2, 3, 5, 10, 5, 3};
  const int NTC[6] = {1, 2, 4, 2, 1, 1};
  const int FOFF[6] = {0, 2, 8, 28, 48, 53};
#pragma unroll
  for (int l = 0; l < 6; ++l) {
    const int cin = CIN[l], cout = COUT[l], lg = LG[l], cinP = 1 << lg;
    const int nst = NST[l];
    const int n = NTC[l] * nst * 512;
    const float* w = wp[l];
    const int base = FOFF[l] * 512;
    for (int i = gid; i < n; i += gstr) {
      const int fid = i >> 9, lane = (i >> 3) & 63, e = i & 7;
      const int nt = fid / nst, st = fid - nt * nst;
      const int o = nt * 16 + (lane & 15);
      const int s = st * 32 + (lane >> 4) * 8 + e;
      const int j = s >> lg, c = s & (cinP - 1);
      float v = 0.f;
      if (o < cout && j < 5 && c < cin) v = w[(o * cin + c) * 5 + j];
      const unsigned short h = f2bf(v);
      wsu[FW_H + base + i] = h;
      wsu[FW_L + base + i] = f2bf(v - bf2f(h));
    }
  }
  for (int i = gid; i < 9 * 512; i += gstr) {  // stage2 32x32 A-frags (isft)
    const int fid = i >> 9, lane = (i >> 3) & 63, e = i & 7;
    const int mt = fid / 3, ks = fid - mt * 3;
    const int p = mt * 32 + (lane & 31);
    const int k = ks * 16 + (lane >> 5) * 8 + e;
    const float v = (p < 90 && k < 45) ? isft[p * 45 + k] : 0.f;
    const unsigned short h = f2bf(v);
    wsu[W2A32_H + i] = h;
    wsu[W2A32_L + i] = f2bf(v - bf2f(h));
  }
  for (int i = gid; i < 9 * 512; i += gstr) {  // stage3 B-frags (scale*sft)
    const int fid = i >> 9, lane = (i >> 3) & 63, e = i & 7;
    const int ntK = fid / 3, sl = fid - ntK * 3;
    const int kk = ntK * 16 + (lane & 15);
    const int p = sl * 32 + (lane >> 4) * 8 + e;
    float v = 0.f;
    if (kk < 45 && p < 90) v = sft[kk * 90 + p] * scale_from_j(lidxf(kk));
    const unsigned short h = f2bf(v);
    wsu[W3B_H + i] = h;
    wsu[W3B_L + i] = f2bf(v - bf2f(h));
  }
}

// stage2 tile, weight-lo dropped: s ~= WI_h · (y_h + y_l); ks=0 A-frag preloaded.
__device__ __forceinline__ f16v s2tile_pre(const unsigned short* U,
                                           const unsigned short* fh, int nt, int lof,
                                           bh8 pah) {
  f16v a;
#pragma unroll
  for (int e = 0; e < 16; ++e) a[e] = 0.f;
  const unsigned short* yb = U + SHo + nt * 3 * 512 + lof;
  {
    const bh8 bhv = *(const bh8*)&yb[0];
    const bh8 blv = *(const bh8*)&yb[SLo - SHo];
    a = __builtin_amdgcn_mfma_f32_32x32x16_bf16(pah, bhv, a, 0, 0, 0);
    a = __builtin_amdgcn_mfma_f32_32x32x16_bf16(pah, blv, a, 0, 0, 0);
  }
#pragma unroll
  for (int ks = 1; ks < 3; ++ks) {
    const bh8 ah = *(const bh8*)&fh[ks * 512];
    const bh8 bhv = *(const bh8*)&yb[ks * 512];
    const bh8 blv = *(const bh8*)&yb[(SLo - SHo) + ks * 512];
    a = __builtin_amdgcn_mfma_f32_32x32x16_bf16(ah, bhv, a, 0, 0, 0);
    a = __builtin_amdgcn_mfma_f32_32x32x16_bf16(ah, blv, a, 0, 0, 0);
  }
  return a;
}
// write s (ReLU'd) into stage-(d) A-frag layout at plane offset soff.
__device__ __forceinline__ void writes_s(unsigned short* U, f16v acc, int mt,
                                         int nt, int llo, int lhi, int soff) {
  const int so = soff + ((nt * 2 + (llo >> 4)) * 3 + mt) * 512 + (llo & 15) * 8 + lhi * 4;
#pragma unroll
  for (int g = 0; g < 4; ++g) {
    const int off = so + g * 128;
    split_store4(&U[SHo + off], &U[SLo + off],
                 fmaxf(acc[g * 4 + 0], 0.f), fmaxf(acc[g * 4 + 1], 0.f),
                 fmaxf(acc[g * 4 + 2], 0.f), fmaxf(acc[g * 4 + 3], 0.f));
  }
}

// ---- stage (a) tile: weight-lo dropped; two independent accumulator chains
// (xh-chain and xl-chain) halve MFMA dependency depth.
template <int layer, int mt>
__device__ __forceinline__ void atile(unsigned short* U,
                                      const unsigned short* __restrict__ wsu,
                                      int nt, int l15, int q4, int lof) {
  constexpr int lg   = (layer == 0) ? 3 : (layer == 1) ? 4 : (layer == 2) ? 5
                     : (layer == 3) ? 6 : (layer == 4) ? 5 : 4;
  constexpr int cinP = 1 << lg;
  constexpr int NSTc = (layer == 0) ? 2 : (layer == 1) ? 3 : (layer == 2) ? 5
                     : (layer == 3) ? 10 : (layer == 4) ? 5 : 3;
  constexpr int FOFFc= (layer == 0) ? 0 : (layer == 1) ? 2 : (layer == 2) ? 8
                     : (layer == 3) ? 28 : (layer == 4) ? 48 : 53;
  constexpr int hi5 = (5 * cinP + 31) >> 5;
  constexpr int hi4 = (4 * cinP + 31) >> 5;
  constexpr int lo3 = (3 * cinP) >> 5;
  constexpr int lo4 = cinP >> 3;
  constexpr int lo = (mt == 0) ? 0 : (mt == 1) ? lo3 : lo4;
  constexpr int hi = (mt == 0) ? hi4 : hi5;
  (void)cinP;

  const int k = mt * 16 + l15;
  const int jb = lidxf(k) << lg;
  const unsigned short* wfh = wsu + FW_H + (FOFFc + nt * NSTc) * 512 + lof;
  f4v aH, aL;
  aH[0] = aH[1] = aH[2] = aH[3] = 0.f;
  aL[0] = aL[1] = aL[2] = aL[3] = 0.f;
#pragma unroll
  for (int st = lo; st < hi; ++st) {
    const int S = st * 32 + q4 * 8;
    const unsigned c0 = (unsigned)(S - jb);
    const unsigned cc = c0 < 64u ? c0 : 64u;  // OOB -> zero pad col
    const unsigned short* xp = &U[XHo + k * 72 + (int)cc];
    const bh8 xh = *(const bh8*)xp;
    const bh8 xl = *(const bh8*)(xp + (XLo - XHo));
    const bh8 wh = *(const bh8*)&wfh[st * 512];
    aH = __builtin_amdgcn_mfma_f32_16x16x32_bf16(xh, wh, aH, 0, 0, 0);
    aL = __builtin_amdgcn_mfma_f32_16x16x32_bf16(xl, wh, aL, 0, 0, 0);
  }
  const f4v a = aH + aL;
  const int off = (((nt >> 1) * 3 + mt) << 9) +
                  ((q4 >> 1) * 32 + (nt & 1) * 16 + l15) * 8 + (q4 & 1) * 4;
  split_store4(&U[SHo + off], &U[SLo + off], a[0], a[1], a[2], a[3]);
}

__device__ __forceinline__ void dstore(unsigned short* U, f4v a, int ntK, int mtO,
                                       int l15, int q4, int layer_zero_mode) {
  const int kk = ntK * 16 + l15;
  const int oc = mtO * 16 + q4 * 4;
  split_store4(&U[XHo + kk * 72 + oc], &U[XLo + kk * 72 + oc],
               a[0], a[1], a[2], a[3]);
  if (layer_zero_mode == 1) {  // next layer cinP=32: cols 32-63 must be zero
    const uint2 z = make_uint2(0u, 0u);
    *(uint2*)&U[XHo + kk * 72 + oc + 32] = z;
    *(uint2*)&U[XLo + kk * 72 + oc + 32] = z;
  }
  if (layer_zero_mode == 2) {  // next layer cinP=16: cols 16-31 must be zero
    const uint2 z = make_uint2(0u, 0u);
    *(uint2*)&U[XHo + kk * 72 + oc + 16] = z;
    *(uint2*)&U[XLo + kk * 72 + oc + 16] = z;
  }
}

// ======================= per-layer body =======================
template <int layer>
__device__ __forceinline__ void layer_body(unsigned short* U,
                                           const unsigned short* __restrict__ wsu,
                                           int tid, int wv, int llo, int lhi,
                                           int l15, int q4, int lof) {
  constexpr int nt16 = (layer == 2) ? 4 : (layer == 1 || layer == 3) ? 2 : 1;
  constexpr int n32  = (layer == 2) ? 2 : 1;
  constexpr int soff = (layer == 2) ? 0 : 3072;  // disjoint s region unless L2
  constexpr int zmode = (layer == 3) ? 1 : (layer == 4) ? 2 : 0;

  // ---- (a) sconv via MFMA -> y B-frags
  {
    constexpr int T = 3 * nt16;
    for (int t = wv; t < T; t += 8) {
      const int mt = t % 3, nt = t / 3;
      if (mt == 0)      atile<layer, 0>(U, wsu, nt, l15, q4, lof);
      else if (mt == 1) atile<layer, 1>(U, wsu, nt, l15, q4, lof);
      else              atile<layer, 2>(U, wsu, nt, l15, q4, lof);
    }
  }
  // ---- preload stage-b ks=0 A-frag (global, no LDS dep) across barrier
  constexpr int T2 = 3 * n32;
  const bool hA = wv < T2;
  const unsigned short* fh = wsu + W2A32_H + (wv % 3) * 3 * 512 + lof;
  bh8 pah;
  if (hA) pah = *(const bh8*)&fh[0];
  __syncthreads();  // end of stage (a)

  // ---- (b)+(c) stage2 MFMA; mid barrier ONLY for layer 2 (y/s overlap)
  {
    f16v a0;
    if (hA) a0 = s2tile_pre(U, fh, wv / 3, lof, pah);
    if constexpr (layer == 2) __syncthreads();
    if (hA) writes_s(U, a0, wv % 3, wv / 3, llo, lhi, soff);
  }
  // ---- preload stage-d sl=0 B-frag for this group's first ntK
  const int grp = wv >> 2, mtO = wv & 3;
  const bool hD = mtO < nt16;
  const int ntKa = (grp == 0) ? 0 : 2;
  const unsigned short* fba = wsu + W3B_H + ntKa * 3 * 512 + lof;
  bh8 pb;
  if (hD) pb = *(const bh8*)&fba[0];
  __syncthreads();  // end of stage (b)

  // ---- (d) stage3 MFMA, weight-lo dropped: X' ~= (s_h + s_l) · WS_h.
  //      grp0 waves own ntK{0,1} (two accs, shared s reads); grp1 own ntK{2}.
  if (hD) {
    const unsigned short* ab = U + SHo + soff + mtO * 3 * 512 + lof;
    if (grp == 0) {
      const unsigned short* fbb = wsu + W3B_H + 3 * 512 + lof;  // ntK=1
      f4v a0, a1;
      a0[0] = a0[1] = a0[2] = a0[3] = 0.f;
      a1[0] = a1[1] = a1[2] = a1[3] = 0.f;
#pragma unroll
      for (int sl = 0; sl < 3; ++sl) {
        const bh8 ah = *(const bh8*)&ab[sl * 512];
        const bh8 al = *(const bh8*)&ab[(SLo - SHo) + sl * 512];
        bh8 b0h;
        if (sl == 0) b0h = pb;
        else         b0h = *(const bh8*)&fba[sl * 512];
        const bh8 b1h = *(const bh8*)&fbb[sl * 512];
        a0 = __builtin_amdgcn_mfma_f32_16x16x32_bf16(ah, b0h, a0, 0, 0, 0);
        a0 = __builtin_amdgcn_mfma_f32_16x16x32_bf16(al, b0h, a0, 0, 0, 0);
        a1 = __builtin_amdgcn_mfma_f32_16x16x32_bf16(ah, b1h, a1, 0, 0, 0);
        a1 = __builtin_amdgcn_mfma_f32_16x16x32_bf16(al, b1h, a1, 0, 0, 0);
      }
      dstore(U, a0, 0, mtO, l15, q4, zmode);
      dstore(U, a1, 1, mtO, l15, q4, zmode);
    } else {
      f4v a;
      a[0] = a[1] = a[2] = a[3] = 0.f;
#pragma unroll
      for (int sl = 0; sl < 3; ++sl) {
        const bh8 ah = *(const bh8*)&ab[sl * 512];
        const bh8 al = *(const bh8*)&ab[(SLo - SHo) + sl * 512];
        bh8 bh_;
        if (sl == 0) bh_ = pb;
        else         bh_ = *(const bh8*)&fba[sl * 512];
        a = __builtin_amdgcn_mfma_f32_16x16x32_bf16(ah, bh_, a, 0, 0, 0);
        a = __builtin_amdgcn_mfma_f32_16x16x32_bf16(al, bh_, a, 0, 0, 0);
      }
      dstore(U, a, 2, mtO, l15, q4, zmode);
    }
  }
  __syncthreads();  // end of stage (d)
}

// ======================= main kernel =======================
__global__ __launch_bounds__(NT, 8)
void scnn_main(const float* __restrict__ xin, const unsigned short* __restrict__ wsu,
               float* __restrict__ out) {
  __shared__ __align__(16) unsigned short U[NU];
  const int tid = threadIdx.x, b = blockIdx.x;
  const int lane = tid & 63, wv = tid >> 6;
  const int llo = lane & 31, lhi = lane >> 5;
  const int l15 = lane & 15, q4 = lane >> 4;
  const int lof = lane << 3;

  // ---- zero-fill entire X region (both planes contiguous: 6912 ush = 1728 uint2)
  for (int i = tid; i < 1728; i += NT)
    ((uint2*)&U[XHo])[i] = make_uint2(0u, 0u);
  __syncthreads();
  // ---- stage initial X: [k][c] stride 72, live cols 0..3, scale-folded
  for (int i = tid; i < 180; i += NT) {
    const int c = i / 45, k = i - c * 45;
    const float v = xin[(size_t)b * 180 + i] * scale_from_j(lidxf(k));
    const unsigned u = __float_as_uint(v);
    const unsigned short h = (unsigned short)(u >> 16);
    U[XHo + k * 72 + c] = h;
    U[XLo + k * 72 + c] = f2bf(v - bf2f(h));
  }
  __syncthreads();

  layer_body<0>(U, wsu, tid, wv, llo, lhi, l15, q4, lof);
  layer_body<1>(U, wsu, tid, wv, llo, lhi, l15, q4, lof);
  layer_body<2>(U, wsu, tid, wv, llo, lhi, l15, q4, lof);
  layer_body<3>(U, wsu, tid, wv, llo, lhi, l15, q4, lof);
  layer_body<4>(U, wsu, tid, wv, llo, lhi, l15, q4, lof);
  layer_body<5>(U, wsu, tid, wv, llo, lhi, l15, q4, lof);

  // ---- epilogue: out[b][c][k] = (XH+XL)[k][c] * (1/scale[k])
  for (int i = tid; i < 180; i += NT) {
    const int c = i / 45, k = i - c * 45;
    const float v = bf2f(U[XHo + k * 72 + c]) + bf2f(U[XLo + k * 72 + c]);
    out[(size_t)b * 180 + i] = v * rcp_from_j(lidxf(k));
  }
}

extern "C" void kernel_launch(void* const* d_in, const int* in_sizes, int n_in,
                              void* d_out, int out_size, void* d_ws, size_t ws_size,
                              hipStream_t stream) {
  (void)n_in; (void)out_size; (void)ws_size;
  const float* x    = (const float*)d_in[0];
  const float* sft  = (const float*)d_in[1];
  const float* isft = (const float*)d_in[2];
  const float* w1   = (const float*)d_in[3];
  const float* w2   = (const float*)d_in[4];
  const float* w3   = (const float*)d_in[5];
  const float* w4   = (const float*)d_in[6];
  const float* w5   = (const float*)d_in[7];
  const float* w6   = (const float*)d_in[8];
  float* out = (float*)d_out;
  unsigned short* wsu = (unsigned short*)d_ws;  // uses 151552 B of scratch
  const int nb = in_sizes[0] / 180;             // 50000
  scnn_prep<<<64, NT, 0, stream>>>(sft, isft, w1, w2, w3, w4, w5, w6, wsu);
  scnn_main<<<nb, NT, 0, stream>>>(x, wsu, out);
}

// Round 14
// 711.507 us; speedup vs baseline: 1.4283x; 1.1225x over previous
//
#include <hip/hip_runtime.h>

#define NT 512

typedef __attribute__((ext_vector_type(8)))  short bh8;   // 8 bf16
typedef __attribute__((ext_vector_type(16))) float f16v;  // 32x32 acc
typedef __attribute__((ext_vector_type(4)))  float f4v;   // 16x16 acc
typedef __attribute__((ext_vector_type(2)))  float f2;    // packed f32 pair

// ---- d_ws layout (ushort units): pre-swizzled 64-lane x 16B fragment dumps.
#define FW_H    0      // sconv expanded-weight B-frags, 56 frags (28672)
#define FW_L    28672
#define W2A32_H 57344  // stage2 32x32 A-frags (isft), 9 frags (4608)
#define W2A32_L 61952
#define W3B_H   66560  // stage3 B-frags (scale*sft), 9 frags (4608)
#define W3B_L   71168  // end 75776 ush = 151552 B

// ---- LDS layout (ushort units) ----
// y frags single-plane (RNE bf16) at YHo; s frags single-plane at S2o —
// disjoint for ALL layers (no mid-(b) barrier anywhere). X stays split
// (hi+lo planes) as the inter-layer carry, zero-padded OOB columns.
#define YHo  0      // y B-frags, up to 6 frags (3072)
#define S2o  3072   // s A-frags, up to 12 frags (6144)
#define XHo  9216   // x planes [k][c] stride 72 (3456)
#define XLo  12672
#define NU   16128  // 32256 B -> 4 blocks/CU (512 thr: 32 waves/CU)

__device__ __forceinline__ unsigned short f2bf(float f) {  // RNE
  unsigned u = __float_as_uint(f);
  return (unsigned short)((u + 0x7fffu + ((u >> 16) & 1u)) >> 16);
}
__device__ __forceinline__ float bf2f(unsigned short h) {
  return __uint_as_float(((unsigned)h) << 16);
}
__device__ __forceinline__ int lidxf(int k) {  // degree band l/2 for coeff k
  return (k < 1) ? 0 : (k < 6) ? 1 : (k < 15) ? 2 : (k < 28) ? 3 : 4;
}
__device__ __forceinline__ float scale_from_j(int j) {  // sqrt(pi/(4j+1))
  float s = 1.7724539f;
  s = (j == 1) ? 0.79266548f : s;
  s = (j == 2) ? 0.59081795f : s;
  s = (j == 3) ? 0.49159026f : s;
  s = (j >= 4) ? 0.42988324f : s;
  return s;
}
__device__ __forceinline__ float rcp_from_j(int j) {  // 1/scale
  float s = 0.56418958f;
  s = (j == 1) ? 1.2615663f : s;
  s = (j == 2) ? 1.6925688f : s;
  s = (j == 3) ? 2.0342144f : s;
  s = (j >= 4) ? 2.3262120f : s;
  return s;
}
// packed split: hi = trunc-bf16 pair via v_perm; lo = trunc(v - bf2f(hi)) pair
__device__ __forceinline__ unsigned pk_hi(float a, float b) {
  return __builtin_amdgcn_perm(__float_as_uint(b), __float_as_uint(a), 0x07060302u);
}
__device__ __forceinline__ void split_store4(unsigned short* dh, unsigned short* dl,
                                             float v0, float v1, float v2, float v3) {
  f2 a01, a23, t01, t23;
  a01[0] = v0; a01[1] = v1; a23[0] = v2; a23[1] = v3;
  t01[0] = __uint_as_float(__float_as_uint(v0) & 0xffff0000u);
  t01[1] = __uint_as_float(__float_as_uint(v1) & 0xffff0000u);
  t23[0] = __uint_as_float(__float_as_uint(v2) & 0xffff0000u);
  t23[1] = __uint_as_float(__float_as_uint(v3) & 0xffff0000u);
  const f2 d01 = a01 - t01, d23 = a23 - t23;  // v_pk_add_f32
  *(uint2*)dh = make_uint2(pk_hi(v0, v1), pk_hi(v2, v3));
  *(uint2*)dl = make_uint2(pk_hi(d01[0], d01[1]), pk_hi(d23[0], d23[1]));
}
// single-plane RNE store of 4 bf16 (one b64 write)
__device__ __forceinline__ void store4h(unsigned short* dh,
                                        float v0, float v1, float v2, float v3) {
  const unsigned w0 = (unsigned)f2bf(v0) | ((unsigned)f2bf(v1) << 16);
  const unsigned w1 = (unsigned)f2bf(v2) | ((unsigned)f2bf(v3) << 16);
  *(uint2*)dh = make_uint2(w0, w1);
}

// ======================= pre-kernel: build fragment dumps =======================
__global__ void scnn_prep(const float* __restrict__ sft, const float* __restrict__ isft,
                          const float* __restrict__ w1, const float* __restrict__ w2,
                          const float* __restrict__ w3, const float* __restrict__ w4,
                          const float* __restrict__ w5, const float* __restrict__ w6,
                          unsigned short* __restrict__ wsu) {
  const int gid = blockIdx.x * NT + threadIdx.x;
  const int gstr = gridDim.x * NT;
  const float* wp[6] = {w1, w2, w3, w4, w5, w6};
  const int CIN[6] = {4, 16, 32, 64, 32, 16};
  const int COUT[6] = {16, 32, 64, 32, 16, 4};
  const int LG[6] = {3, 4, 5, 6, 5, 4};
  const int NST[6] = {2, 3, 5, 10, 5, 3};
  const int NTC[6] = {1, 2, 4, 2, 1, 1};
  const int FOFF[6] = {0, 2, 8, 28, 48, 53};
#pragma unroll
  for (int l = 0; l < 6; ++l) {
    const int cin = CIN[l], cout = COUT[l], lg = LG[l], cinP = 1 << lg;
    const int nst = NST[l];
    const int n = NTC[l] * nst * 512;
    const float* w = wp[l];
    const int base = FOFF[l] * 512;
    for (int i = gid; i < n; i += gstr) {
      const int fid = i >> 9, lane = (i >> 3) & 63, e = i & 7;
      const int nt = fid / nst, st = fid - nt * nst;
      const int o = nt * 16 + (lane & 15);
      const int s = st * 32 + (lane >> 4) * 8 + e;
      const int j = s >> lg, c = s & (cinP - 1);
      float v = 0.f;
      if (o < cout && j < 5 && c < cin) v = w[(o * cin + c) * 5 + j];
      const unsigned short h = f2bf(v);
      wsu[FW_H + base + i] = h;
      wsu[FW_L + base + i] = f2bf(v - bf2f(h));
    }
  }
  for (int i = gid; i < 9 * 512; i += gstr) {  // stage2 32x32 A-frags (isft)
    const int fid = i >> 9, lane = (i >> 3) & 63, e = i & 7;
    const int mt = fid / 3, ks = fid - mt * 3;
    const int p = mt * 32 + (lane & 31);
    const int k = ks * 16 + (lane >> 5) * 8 + e;
    const float v = (p < 90 && k < 45) ? isft[p * 45 + k] : 0.f;
    const unsigned short h = f2bf(v);
    wsu[W2A32_H + i] = h;
    wsu[W2A32_L + i] = f2bf(v - bf2f(h));
  }
  for (int i = gid; i < 9 * 512; i += gstr) {  // stage3 B-frags (scale*sft)
    const int fid = i >> 9, lane = (i >> 3) & 63, e = i & 7;
    const int ntK = fid / 3, sl = fid - ntK * 3;
    const int kk = ntK * 16 + (lane & 15);
    const int p = sl * 32 + (lane >> 4) * 8 + e;
    float v = 0.f;
    if (kk < 45 && p < 90) v = sft[kk * 90 + p] * scale_from_j(lidxf(kk));
    const unsigned short h = f2bf(v);
    wsu[W3B_H + i] = h;
    wsu[W3B_L + i] = f2bf(v - bf2f(h));
  }
}

// stage2 tile: s ~= WI_h · y_h (y single-plane); ks=0 A-frag preloaded. 3-chain.
__device__ __forceinline__ f16v s2tile_pre(const unsigned short* U,
                                           const unsigned short* fh, int nt, int lof,
                                           bh8 pah) {
  f16v a;
#pragma unroll
  for (int e = 0; e < 16; ++e) a[e] = 0.f;
  const unsigned short* yb = U + YHo + nt * 3 * 512 + lof;
  {
    const bh8 bhv = *(const bh8*)&yb[0];
    a = __builtin_amdgcn_mfma_f32_32x32x16_bf16(pah, bhv, a, 0, 0, 0);
  }
#pragma unroll
  for (int ks = 1; ks < 3; ++ks) {
    const bh8 ah = *(const bh8*)&fh[ks * 512];
    const bh8 bhv = *(const bh8*)&yb[ks * 512];
    a = __builtin_amdgcn_mfma_f32_32x32x16_bf16(ah, bhv, a, 0, 0, 0);
  }
  return a;
}
// write s (ReLU'd, RNE bf16 single-plane) into stage-(d) A-frag layout.
__device__ __forceinline__ void writes_s(unsigned short* U, f16v acc, int mt,
                                         int nt, int llo, int lhi) {
  const int so = S2o + ((nt * 2 + (llo >> 4)) * 3 + mt) * 512 + (llo & 15) * 8 + lhi * 4;
#pragma unroll
  for (int g = 0; g < 4; ++g) {
    store4h(&U[so + g * 128],
            fmaxf(acc[g * 4 + 0], 0.f), fmaxf(acc[g * 4 + 1], 0.f),
            fmaxf(acc[g * 4 + 2], 0.f), fmaxf(acc[g * 4 + 3], 0.f));
  }
}

// ---- stage (a) tile: weight-lo dropped; two independent accumulator chains
// (xh-chain and xl-chain). Output y stored RNE single-plane.
template <int layer, int mt>
__device__ __forceinline__ void atile(unsigned short* U,
                                      const unsigned short* __restrict__ wsu,
                                      int nt, int l15, int q4, int lof) {
  constexpr int lg   = (layer == 0) ? 3 : (layer == 1) ? 4 : (layer == 2) ? 5
                     : (layer == 3) ? 6 : (layer == 4) ? 5 : 4;
  constexpr int cinP = 1 << lg;
  constexpr int NSTc = (layer == 0) ? 2 : (layer == 1) ? 3 : (layer == 2) ? 5
                     : (layer == 3) ? 10 : (layer == 4) ? 5 : 3;
  constexpr int FOFFc= (layer == 0) ? 0 : (layer == 1) ? 2 : (layer == 2) ? 8
                     : (layer == 3) ? 28 : (layer == 4) ? 48 : 53;
  constexpr int hi5 = (5 * cinP + 31) >> 5;
  constexpr int hi4 = (4 * cinP + 31) >> 5;
  constexpr int lo3 = (3 * cinP) >> 5;
  constexpr int lo4 = cinP >> 3;
  constexpr int lo = (mt == 0) ? 0 : (mt == 1) ? lo3 : lo4;
  constexpr int hi = (mt == 0) ? hi4 : hi5;
  (void)cinP;

  const int k = mt * 16 + l15;
  const int jb = lidxf(k) << lg;
  const unsigned short* wfh = wsu + FW_H + (FOFFc + nt * NSTc) * 512 + lof;
  f4v aH, aL;
  aH[0] = aH[1] = aH[2] = aH[3] = 0.f;
  aL[0] = aL[1] = aL[2] = aL[3] = 0.f;
#pragma unroll
  for (int st = lo; st < hi; ++st) {
    const int S = st * 32 + q4 * 8;
    const unsigned c0 = (unsigned)(S - jb);
    const unsigned cc = c0 < 64u ? c0 : 64u;  // OOB -> zero pad col
    const unsigned short* xp = &U[XHo + k * 72 + (int)cc];
    const bh8 xh = *(const bh8*)xp;
    const bh8 xl = *(const bh8*)(xp + (XLo - XHo));
    const bh8 wh = *(const bh8*)&wfh[st * 512];
    aH = __builtin_amdgcn_mfma_f32_16x16x32_bf16(xh, wh, aH, 0, 0, 0);
    aL = __builtin_amdgcn_mfma_f32_16x16x32_bf16(xl, wh, aL, 0, 0, 0);
  }
  const f4v a = aH + aL;
  const int off = (((nt >> 1) * 3 + mt) << 9) +
                  ((q4 >> 1) * 32 + (nt & 1) * 16 + l15) * 8 + (q4 & 1) * 4;
  store4h(&U[YHo + off], a[0], a[1], a[2], a[3]);
}

__device__ __forceinline__ void dstore(unsigned short* U, f4v a, int ntK, int mtO,
                                       int l15, int q4, int layer_zero_mode) {
  const int kk = ntK * 16 + l15;
  const int oc = mtO * 16 + q4 * 4;
  split_store4(&U[XHo + kk * 72 + oc], &U[XLo + kk * 72 + oc],
               a[0], a[1], a[2], a[3]);
  if (layer_zero_mode == 1) {  // next layer cinP=32: cols 32-63 must be zero
    const uint2 z = make_uint2(0u, 0u);
    *(uint2*)&U[XHo + kk * 72 + oc + 32] = z;
    *(uint2*)&U[XLo + kk * 72 + oc + 32] = z;
  }
  if (layer_zero_mode == 2) {  // next layer cinP=16: cols 16-31 must be zero
    const uint2 z = make_uint2(0u, 0u);
    *(uint2*)&U[XHo + kk * 72 + oc + 16] = z;
    *(uint2*)&U[XLo + kk * 72 + oc + 16] = z;
  }
}

// ======================= per-layer body =======================
template <int layer>
__device__ __forceinline__ void layer_body(unsigned short* U,
                                           const unsigned short* __restrict__ wsu,
                                           int tid, int wv, int llo, int lhi,
                                           int l15, int q4, int lof) {
  constexpr int nt16 = (layer == 2) ? 4 : (layer == 1 || layer == 3) ? 2 : 1;
  constexpr int n32  = (layer == 2) ? 2 : 1;
  constexpr int zmode = (layer == 3) ? 1 : (layer == 4) ? 2 : 0;

  // ---- (a) sconv via MFMA -> y B-frags (single plane)
  {
    constexpr int T = 3 * nt16;
    for (int t = wv; t < T; t += 8) {
      const int mt = t % 3, nt = t / 3;
      if (mt == 0)      atile<layer, 0>(U, wsu, nt, l15, q4, lof);
      else if (mt == 1) atile<layer, 1>(U, wsu, nt, l15, q4, lof);
      else              atile<layer, 2>(U, wsu, nt, l15, q4, lof);
    }
  }
  // ---- preload stage-b ks=0 A-frag (global, no LDS dep) across barrier
  constexpr int T2 = 3 * n32;
  const bool hA = wv < T2;
  const unsigned short* fh = wsu + W2A32_H + (wv % 3) * 3 * 512 + lof;
  bh8 pah;
  if (hA) pah = *(const bh8*)&fh[0];
  __syncthreads();  // end of stage (a)

  // ---- (b)+(c) stage2 MFMA; y and s regions disjoint -> no mid barrier
  {
    f16v a0;
    if (hA) a0 = s2tile_pre(U, fh, wv / 3, lof, pah);
    if (hA) writes_s(U, a0, wv % 3, wv / 3, llo, lhi);
  }
  // ---- preload stage-d sl=0 B-frag for this group's first ntK
  const int grp = wv >> 2, mtO = wv & 3;
  const bool hD = mtO < nt16;
  const int ntKa = (grp == 0) ? 0 : 2;
  const unsigned short* fba = wsu + W3B_H + ntKa * 3 * 512 + lof;
  bh8 pb;
  if (hD) pb = *(const bh8*)&fba[0];
  __syncthreads();  // end of stage (b)

  // ---- (d) stage3 MFMA: X' ~= s_h · WS_h (s single-plane).
  //      grp0 waves own ntK{0,1} (two accs, shared s reads); grp1 own ntK{2}.
  if (hD) {
    const unsigned short* ab = U + S2o + mtO * 3 * 512 + lof;
    if (grp == 0) {
      const unsigned short* fbb = wsu + W3B_H + 3 * 512 + lof;  // ntK=1
      f4v a0, a1;
      a0[0] = a0[1] = a0[2] = a0[3] = 0.f;
      a1[0] = a1[1] = a1[2] = a1[3] = 0.f;
#pragma unroll
      for (int sl = 0; sl < 3; ++sl) {
        const bh8 ah = *(const bh8*)&ab[sl * 512];
        bh8 b0h;
        if (sl == 0) b0h = pb;
        else         b0h = *(const bh8*)&fba[sl * 512];
        const bh8 b1h = *(const bh8*)&fbb[sl * 512];
        a0 = __builtin_amdgcn_mfma_f32_16x16x32_bf16(ah, b0h, a0, 0, 0, 0);
        a1 = __builtin_amdgcn_mfma_f32_16x16x32_bf16(ah, b1h, a1, 0, 0, 0);
      }
      dstore(U, a0, 0, mtO, l15, q4, zmode);
      dstore(U, a1, 1, mtO, l15, q4, zmode);
    } else {
      f4v a;
      a[0] = a[1] = a[2] = a[3] = 0.f;
#pragma unroll
      for (int sl = 0; sl < 3; ++sl) {
        const bh8 ah = *(const bh8*)&ab[sl * 512];
        bh8 bh_;
        if (sl == 0) bh_ = pb;
        else         bh_ = *(const bh8*)&fba[sl * 512];
        a = __builtin_amdgcn_mfma_f32_16x16x32_bf16(ah, bh_, a, 0, 0, 0);
      }
      dstore(U, a, 2, mtO, l15, q4, zmode);
    }
  }
  __syncthreads();  // end of stage (d)
}

// ======================= main kernel =======================
__global__ __launch_bounds__(NT, 8)
void scnn_main(const float* __restrict__ xin, const unsigned short* __restrict__ wsu,
               float* __restrict__ out) {
  __shared__ __align__(16) unsigned short U[NU];
  const int tid = threadIdx.x, b = blockIdx.x;
  const int lane = tid & 63, wv = tid >> 6;
  const int llo = lane & 31, lhi = lane >> 5;
  const int l15 = lane & 15, q4 = lane >> 4;
  const int lof = lane << 3;

  // ---- zero-fill entire X region (both planes contiguous: 6912 ush = 1728 uint2)
  for (int i = tid; i < 1728; i += NT)
    ((uint2*)&U[XHo])[i] = make_uint2(0u, 0u);
  __syncthreads();
  // ---- stage initial X: [k][c] stride 72, live cols 0..3, scale-folded
  for (int i = tid; i < 180; i += NT) {
    const int c = i / 45, k = i - c * 45;
    const float v = xin[(size_t)b * 180 + i] * scale_from_j(lidxf(k));
    const unsigned u = __float_as_uint(v);
    const unsigned short h = (unsigned short)(u >> 16);
    U[XHo + k * 72 + c] = h;
    U[XLo + k * 72 + c] = f2bf(v - bf2f(h));
  }
  __syncthreads();

  layer_body<0>(U, wsu, tid, wv, llo, lhi, l15, q4, lof);
  layer_body<1>(U, wsu, tid, wv, llo, lhi, l15, q4, lof);
  layer_body<2>(U, wsu, tid, wv, llo, lhi, l15, q4, lof);
  layer_body<3>(U, wsu, tid, wv, llo, lhi, l15, q4, lof);
  layer_body<4>(U, wsu, tid, wv, llo, lhi, l15, q4, lof);
  layer_body<5>(U, wsu, tid, wv, llo, lhi, l15, q4, lof);

  // ---- epilogue: out[b][c][k] = (XH+XL)[k][c] * (1/scale[k])
  for (int i = tid; i < 180; i += NT) {
    const int c = i / 45, k = i - c * 45;
    const float v = bf2f(U[XHo + k * 72 + c]) + bf2f(U[XLo + k * 72 + c]);
    out[(size_t)b * 180 + i] = v * rcp_from_j(lidxf(k));
  }
}

extern "C" void kernel_launch(void* const* d_in, const int* in_sizes, int n_in,
                              void* d_out, int out_size, void* d_ws, size_t ws_size,
                              hipStream_t stream) {
  (void)n_in; (void)out_size; (void)ws_size;
  const float* x    = (const float*)d_in[0];
  const float* sft  = (const float*)d_in[1];
  const float* isft = (const float*)d_in[2];
  const float* w1   = (const float*)d_in[3];
  const float* w2   = (const float*)d_in[4];
  const float* w3   = (const float*)d_in[5];
  const float* w4   = (const float*)d_in[6];
  const float* w5   = (const float*)d_in[7];
  const float* w6   = (const float*)d_in[8];
  float* out = (float*)d_out;
  unsigned short* wsu = (unsigned short*)d_ws;  // uses 151552 B of scratch
  const int nb = in_sizes[0] / 180;             // 50000
  scnn_prep<<<64, NT, 0, stream>>>(sft, isft, w1, w2, w3, w4, w5, w6, wsu);
  scnn_main<<<nb, NT, 0, stream>>>(x, wsu, out);
}

// Round 15
// 664.943 us; speedup vs baseline: 1.5283x; 1.0700x over previous
//
#include <hip/hip_runtime.h>

#define NT 512

typedef __attribute__((ext_vector_type(8)))  short bh8;   // 8 bf16
typedef __attribute__((ext_vector_type(16))) float f16v;  // 32x32 acc
typedef __attribute__((ext_vector_type(4)))  float f4v;   // 16x16 acc

// ---- d_ws layout (ushort units): pre-swizzled 64-lane x 16B fragment dumps.
#define FW_H    0      // sconv expanded-weight B-frags, 56 frags (28672)
#define FW_L    28672
#define W2A32_H 57344  // stage2 32x32 A-frags (isft), 9 frags (4608)
#define W2A32_L 61952
#define W3B_H   66560  // stage3 B-frags (scale*sft), 9 frags (4608)
#define W3B_L   71168  // end 75776 ush = 151552 B

// ---- LDS layout (ushort units) ----
// ALL activations single-plane RNE bf16 now: y B-frags, s A-frags, and the
// inter-layer X carry [k][c] stride 72 with zero-padded OOB columns.
#define YHo  0      // y B-frags, up to 6 frags (3072)
#define S2o  3072   // s A-frags, up to 12 frags (6144)
#define XHo  9216   // x plane [k][c] stride 72 (3456)
#define NU   12672  // 25344 B -> 4 blocks/CU (512 thr: 32 waves/CU)

__device__ __forceinline__ unsigned short f2bf(float f) {  // RNE
  unsigned u = __float_as_uint(f);
  return (unsigned short)((u + 0x7fffu + ((u >> 16) & 1u)) >> 16);
}
__device__ __forceinline__ float bf2f(unsigned short h) {
  return __uint_as_float(((unsigned)h) << 16);
}
__device__ __forceinline__ int lidxf(int k) {  // degree band l/2 for coeff k
  return (k < 1) ? 0 : (k < 6) ? 1 : (k < 15) ? 2 : (k < 28) ? 3 : 4;
}
__device__ __forceinline__ float scale_from_j(int j) {  // sqrt(pi/(4j+1))
  float s = 1.7724539f;
  s = (j == 1) ? 0.79266548f : s;
  s = (j == 2) ? 0.59081795f : s;
  s = (j == 3) ? 0.49159026f : s;
  s = (j >= 4) ? 0.42988324f : s;
  return s;
}
__device__ __forceinline__ float rcp_from_j(int j) {  // 1/scale
  float s = 0.56418958f;
  s = (j == 1) ? 1.2615663f : s;
  s = (j == 2) ? 1.6925688f : s;
  s = (j == 3) ? 2.0342144f : s;
  s = (j >= 4) ? 2.3262120f : s;
  return s;
}
// single-plane RNE store of 4 bf16 (one b64 write)
__device__ __forceinline__ void store4h(unsigned short* dh,
                                        float v0, float v1, float v2, float v3) {
  const unsigned w0 = (unsigned)f2bf(v0) | ((unsigned)f2bf(v1) << 16);
  const unsigned w1 = (unsigned)f2bf(v2) | ((unsigned)f2bf(v3) << 16);
  *(uint2*)dh = make_uint2(w0, w1);
}

// ======================= pre-kernel: build fragment dumps =======================
__global__ void scnn_prep(const float* __restrict__ sft, const float* __restrict__ isft,
                          const float* __restrict__ w1, const float* __restrict__ w2,
                          const float* __restrict__ w3, const float* __restrict__ w4,
                          const float* __restrict__ w5, const float* __restrict__ w6,
                          unsigned short* __restrict__ wsu) {
  const int gid = blockIdx.x * NT + threadIdx.x;
  const int gstr = gridDim.x * NT;
  const float* wp[6] = {w1, w2, w3, w4, w5, w6};
  const int CIN[6] = {4, 16, 32, 64, 32, 16};
  const int COUT[6] = {16, 32, 64, 32, 16, 4};
  const int LG[6] = {3, 4, 5, 6, 5, 4};
  const int NST[6] = {2, 3, 5, 10, 5, 3};
  const int NTC[6] = {1, 2, 4, 2, 1, 1};
  const int FOFF[6] = {0, 2, 8, 28, 48, 53};
#pragma unroll
  for (int l = 0; l < 6; ++l) {
    const int cin = CIN[l], cout = COUT[l], lg = LG[l], cinP = 1 << lg;
    const int nst = NST[l];
    const int n = NTC[l] * nst * 512;
    const float* w = wp[l];
    const int base = FOFF[l] * 512;
    for (int i = gid; i < n; i += gstr) {
      const int fid = i >> 9, lane = (i >> 3) & 63, e = i & 7;
      const int nt = fid / nst, st = fid - nt * nst;
      const int o = nt * 16 + (lane & 15);
      const int s = st * 32 + (lane >> 4) * 8 + e;
      const int j = s >> lg, c = s & (cinP - 1);
      float v = 0.f;
      if (o < cout && j < 5 && c < cin) v = w[(o * cin + c) * 5 + j];
      const unsigned short h = f2bf(v);
      wsu[FW_H + base + i] = h;
      wsu[FW_L + base + i] = f2bf(v - bf2f(h));
    }
  }
  for (int i = gid; i < 9 * 512; i += gstr) {  // stage2 32x32 A-frags (isft)
    const int fid = i >> 9, lane = (i >> 3) & 63, e = i & 7;
    const int mt = fid / 3, ks = fid - mt * 3;
    const int p = mt * 32 + (lane & 31);
    const int k = ks * 16 + (lane >> 5) * 8 + e;
    const float v = (p < 90 && k < 45) ? isft[p * 45 + k] : 0.f;
    const unsigned short h = f2bf(v);
    wsu[W2A32_H + i] = h;
    wsu[W2A32_L + i] = f2bf(v - bf2f(h));
  }
  for (int i = gid; i < 9 * 512; i += gstr) {  // stage3 B-frags (scale*sft)
    const int fid = i >> 9, lane = (i >> 3) & 63, e = i & 7;
    const int ntK = fid / 3, sl = fid - ntK * 3;
    const int kk = ntK * 16 + (lane & 15);
    const int p = sl * 32 + (lane >> 4) * 8 + e;
    float v = 0.f;
    if (kk < 45 && p < 90) v = sft[kk * 90 + p] * scale_from_j(lidxf(kk));
    const unsigned short h = f2bf(v);
    wsu[W3B_H + i] = h;
    wsu[W3B_L + i] = f2bf(v - bf2f(h));
  }
}

// stage2 tile: s ~= WI_h · y_h (y single-plane); ks=0 A-frag preloaded. 3-chain.
__device__ __forceinline__ f16v s2tile_pre(const unsigned short* U,
                                           const unsigned short* fh, int nt, int lof,
                                           bh8 pah) {
  f16v a;
#pragma unroll
  for (int e = 0; e < 16; ++e) a[e] = 0.f;
  const unsigned short* yb = U + YHo + nt * 3 * 512 + lof;
  {
    const bh8 bhv = *(const bh8*)&yb[0];
    a = __builtin_amdgcn_mfma_f32_32x32x16_bf16(pah, bhv, a, 0, 0, 0);
  }
#pragma unroll
  for (int ks = 1; ks < 3; ++ks) {
    const bh8 ah = *(const bh8*)&fh[ks * 512];
    const bh8 bhv = *(const bh8*)&yb[ks * 512];
    a = __builtin_amdgcn_mfma_f32_32x32x16_bf16(ah, bhv, a, 0, 0, 0);
  }
  return a;
}
// write s (ReLU'd, RNE bf16 single-plane) into stage-(d) A-frag layout.
__device__ __forceinline__ void writes_s(unsigned short* U, f16v acc, int mt,
                                         int nt, int llo, int lhi) {
  const int so = S2o + ((nt * 2 + (llo >> 4)) * 3 + mt) * 512 + (llo & 15) * 8 + lhi * 4;
#pragma unroll
  for (int g = 0; g < 4; ++g) {
    store4h(&U[so + g * 128],
            fmaxf(acc[g * 4 + 0], 0.f), fmaxf(acc[g * 4 + 1], 0.f),
            fmaxf(acc[g * 4 + 2], 0.f), fmaxf(acc[g * 4 + 3], 0.f));
  }
}

// ---- stage (a) tile: single-plane X, weight-lo dropped -> 1 MFMA + 1 ds_read
// per st iter, single accumulator chain.
template <int layer, int mt>
__device__ __forceinline__ void atile(unsigned short* U,
                                      const unsigned short* __restrict__ wsu,
                                      int nt, int l15, int q4, int lof) {
  constexpr int lg   = (layer == 0) ? 3 : (layer == 1) ? 4 : (layer == 2) ? 5
                     : (layer == 3) ? 6 : (layer == 4) ? 5 : 4;
  constexpr int cinP = 1 << lg;
  constexpr int NSTc = (layer == 0) ? 2 : (layer == 1) ? 3 : (layer == 2) ? 5
                     : (layer == 3) ? 10 : (layer == 4) ? 5 : 3;
  constexpr int FOFFc= (layer == 0) ? 0 : (layer == 1) ? 2 : (layer == 2) ? 8
                     : (layer == 3) ? 28 : (layer == 4) ? 48 : 53;
  constexpr int hi5 = (5 * cinP + 31) >> 5;
  constexpr int hi4 = (4 * cinP + 31) >> 5;
  constexpr int lo3 = (3 * cinP) >> 5;
  constexpr int lo4 = cinP >> 3;
  constexpr int lo = (mt == 0) ? 0 : (mt == 1) ? lo3 : lo4;
  constexpr int hi = (mt == 0) ? hi4 : hi5;
  (void)cinP;

  const int k = mt * 16 + l15;
  const int jb = lidxf(k) << lg;
  const unsigned short* wfh = wsu + FW_H + (FOFFc + nt * NSTc) * 512 + lof;
  f4v a;
  a[0] = a[1] = a[2] = a[3] = 0.f;
#pragma unroll
  for (int st = lo; st < hi; ++st) {
    const int S = st * 32 + q4 * 8;
    const unsigned c0 = (unsigned)(S - jb);
    const unsigned cc = c0 < 64u ? c0 : 64u;  // OOB -> zero pad col
    const bh8 xh = *(const bh8*)&U[XHo + k * 72 + (int)cc];
    const bh8 wh = *(const bh8*)&wfh[st * 512];
    a = __builtin_amdgcn_mfma_f32_16x16x32_bf16(xh, wh, a, 0, 0, 0);
  }
  const int off = (((nt >> 1) * 3 + mt) << 9) +
                  ((q4 >> 1) * 32 + (nt & 1) * 16 + l15) * 8 + (q4 & 1) * 4;
  store4h(&U[YHo + off], a[0], a[1], a[2], a[3]);
}

__device__ __forceinline__ void dstore(unsigned short* U, f4v a, int ntK, int mtO,
                                       int l15, int q4, int layer_zero_mode) {
  const int kk = ntK * 16 + l15;
  const int oc = mtO * 16 + q4 * 4;
  store4h(&U[XHo + kk * 72 + oc], a[0], a[1], a[2], a[3]);
  if (layer_zero_mode == 1) {  // next layer cinP=32: cols 32-63 must be zero
    *(uint2*)&U[XHo + kk * 72 + oc + 32] = make_uint2(0u, 0u);
  }
  if (layer_zero_mode == 2) {  // next layer cinP=16: cols 16-31 must be zero
    *(uint2*)&U[XHo + kk * 72 + oc + 16] = make_uint2(0u, 0u);
  }
}

// ======================= per-layer body =======================
template <int layer>
__device__ __forceinline__ void layer_body(unsigned short* U,
                                           const unsigned short* __restrict__ wsu,
                                           int tid, int wv, int llo, int lhi,
                                           int l15, int q4, int lof) {
  constexpr int nt16 = (layer == 2) ? 4 : (layer == 1 || layer == 3) ? 2 : 1;
  constexpr int n32  = (layer == 2) ? 2 : 1;
  constexpr int zmode = (layer == 3) ? 1 : (layer == 4) ? 2 : 0;

  // ---- (a) sconv via MFMA -> y B-frags (single plane)
  {
    constexpr int T = 3 * nt16;
    for (int t = wv; t < T; t += 8) {
      const int mt = t % 3, nt = t / 3;
      if (mt == 0)      atile<layer, 0>(U, wsu, nt, l15, q4, lof);
      else if (mt == 1) atile<layer, 1>(U, wsu, nt, l15, q4, lof);
      else              atile<layer, 2>(U, wsu, nt, l15, q4, lof);
    }
  }
  // ---- preload stage-b ks=0 A-frag (global, no LDS dep) across barrier
  constexpr int T2 = 3 * n32;
  const bool hA = wv < T2;
  const unsigned short* fh = wsu + W2A32_H + (wv % 3) * 3 * 512 + lof;
  bh8 pah;
  if (hA) pah = *(const bh8*)&fh[0];
  __syncthreads();  // end of stage (a)

  // ---- (b)+(c) stage2 MFMA; y and s regions disjoint -> no mid barrier
  {
    f16v a0;
    if (hA) a0 = s2tile_pre(U, fh, wv / 3, lof, pah);
    if (hA) writes_s(U, a0, wv % 3, wv / 3, llo, lhi);
  }
  // ---- preload stage-d sl=0 B-frag for this group's first ntK
  const int grp = wv >> 2, mtO = wv & 3;
  const bool hD = mtO < nt16;
  const int ntKa = (grp == 0) ? 0 : 2;
  const unsigned short* fba = wsu + W3B_H + ntKa * 3 * 512 + lof;
  bh8 pb;
  if (hD) pb = *(const bh8*)&fba[0];
  __syncthreads();  // end of stage (b)

  // ---- (d) stage3 MFMA: X' ~= s_h · WS_h (all single-plane).
  //      grp0 waves own ntK{0,1} (two accs, shared s reads); grp1 own ntK{2}.
  if (hD) {
    const unsigned short* ab = U + S2o + mtO * 3 * 512 + lof;
    if (grp == 0) {
      const unsigned short* fbb = wsu + W3B_H + 3 * 512 + lof;  // ntK=1
      f4v a0, a1;
      a0[0] = a0[1] = a0[2] = a0[3] = 0.f;
      a1[0] = a1[1] = a1[2] = a1[3] = 0.f;
#pragma unroll
      for (int sl = 0; sl < 3; ++sl) {
        const bh8 ah = *(const bh8*)&ab[sl * 512];
        bh8 b0h;
        if (sl == 0) b0h = pb;
        else         b0h = *(const bh8*)&fba[sl * 512];
        const bh8 b1h = *(const bh8*)&fbb[sl * 512];
        a0 = __builtin_amdgcn_mfma_f32_16x16x32_bf16(ah, b0h, a0, 0, 0, 0);
        a1 = __builtin_amdgcn_mfma_f32_16x16x32_bf16(ah, b1h, a1, 0, 0, 0);
      }
      dstore(U, a0, 0, mtO, l15, q4, zmode);
      dstore(U, a1, 1, mtO, l15, q4, zmode);
    } else {
      f4v a;
      a[0] = a[1] = a[2] = a[3] = 0.f;
#pragma unroll
      for (int sl = 0; sl < 3; ++sl) {
        const bh8 ah = *(const bh8*)&ab[sl * 512];
        bh8 bh_;
        if (sl == 0) bh_ = pb;
        else         bh_ = *(const bh8*)&fba[sl * 512];
        a = __builtin_amdgcn_mfma_f32_16x16x32_bf16(ah, bh_, a, 0, 0, 0);
      }
      dstore(U, a, 2, mtO, l15, q4, zmode);
    }
  }
  __syncthreads();  // end of stage (d)
}

// ======================= main kernel =======================
__global__ __launch_bounds__(NT, 8)
void scnn_main(const float* __restrict__ xin, const unsigned short* __restrict__ wsu,
               float* __restrict__ out) {
  __shared__ __align__(16) unsigned short U[NU];
  const int tid = threadIdx.x, b = blockIdx.x;
  const int lane = tid & 63, wv = tid >> 6;
  const int llo = lane & 31, lhi = lane >> 5;
  const int l15 = lane & 15, q4 = lane >> 4;
  const int lof = lane << 3;

  // ---- zero-fill X region (3456 ush = 864 uint2)
  for (int i = tid; i < 864; i += NT)
    ((uint2*)&U[XHo])[i] = make_uint2(0u, 0u);
  __syncthreads();
  // ---- stage initial X: [k][c] stride 72, live cols 0..3, scale-folded, RNE
  for (int i = tid; i < 180; i += NT) {
    const int c = i / 45, k = i - c * 45;
    const float v = xin[(size_t)b * 180 + i] * scale_from_j(lidxf(k));
    U[XHo + k * 72 + c] = f2bf(v);
  }
  __syncthreads();

  layer_body<0>(U, wsu, tid, wv, llo, lhi, l15, q4, lof);
  layer_body<1>(U, wsu, tid, wv, llo, lhi, l15, q4, lof);
  layer_body<2>(U, wsu, tid, wv, llo, lhi, l15, q4, lof);
  layer_body<3>(U, wsu, tid, wv, llo, lhi, l15, q4, lof);
  layer_body<4>(U, wsu, tid, wv, llo, lhi, l15, q4, lof);
  layer_body<5>(U, wsu, tid, wv, llo, lhi, l15, q4, lof);

  // ---- epilogue: out[b][c][k] = X[k][c] * (1/scale[k])
  for (int i = tid; i < 180; i += NT) {
    const int c = i / 45, k = i - c * 45;
    const float v = bf2f(U[XHo + k * 72 + c]);
    out[(size_t)b * 180 + i] = v * rcp_from_j(lidxf(k));
  }
}

extern "C" void kernel_launch(void* const* d_in, const int* in_sizes, int n_in,
                              void* d_out, int out_size, void* d_ws, size_t ws_size,
                              hipStream_t stream) {
  (void)n_in; (void)out_size; (void)ws_size;
  const float* x    = (const float*)d_in[0];
  const float* sft  = (const float*)d_in[1];
  const float* isft = (const float*)d_in[2];
  const float* w1   = (const float*)d_in[3];
  const float* w2   = (const float*)d_in[4];
  const float* w3   = (const float*)d_in[5];
  const float* w4   = (const float*)d_in[6];
  const float* w5   = (const float*)d_in[7];
  const float* w6   = (const float*)d_in[8];
  float* out = (float*)d_out;
  unsigned short* wsu = (unsigned short*)d_ws;  // uses 151552 B of scratch
  const int nb = in_sizes[0] / 180;             // 50000
  scnn_prep<<<64, NT, 0, stream>>>(sft, isft, w1, w2, w3, w4, w5, w6, wsu);
  scnn_main<<<nb, NT, 0, stream>>>(x, wsu, out);
}

// Round 17
// 650.673 us; speedup vs baseline: 1.5618x; 1.0219x over previous
//
#include <hip/hip_runtime.h>

#define NT 512

typedef __attribute__((ext_vector_type(8)))  short bh8;   // 8 bf16
typedef __attribute__((ext_vector_type(16))) float f16v;  // 32x32 acc
typedef __attribute__((ext_vector_type(4)))  float f4v;   // 16x16 acc

// ---- d_ws layout (ushort units): pre-swizzled 64-lane x 16B fragment dumps.
#define FW_H    0      // sconv expanded-weight B-frags, 56 frags (28672)
#define FW_L    28672
#define W2A32_H 57344  // stage2 32x32 A-frags (isft), 9 frags (4608)
#define W2A32_L 61952
#define W3B_H   66560  // stage3 B-frags (scale*sft), 9 frags (4608)
#define W3B_L   71168  // end 75776 ush = 151552 B

// ---- LDS layout (ushort units) ----
// ALL activations single-plane RNE bf16: y B-frags, s A-frags, and the
// inter-layer X carry [k][c] stride 72 with zero-padded OOB columns.
#define YHo  0      // y B-frags, up to 6 frags (3072)
#define S2o  3072   // s A-frags, up to 12 frags (6144)
#define XHo  9216   // x plane [k][c] stride 72 (3456)
#define NU   12672  // 25344 B -> 4 blocks/CU (512 thr: 32 waves/CU)

__device__ __forceinline__ unsigned short f2bf(float f) {  // RNE
  unsigned u = __float_as_uint(f);
  return (unsigned short)((u + 0x7fffu + ((u >> 16) & 1u)) >> 16);
}
__device__ __forceinline__ float bf2f(unsigned short h) {
  return __uint_as_float(((unsigned)h) << 16);
}
__device__ __forceinline__ int lidxf(int k) {  // degree band l/2 for coeff k
  return (k < 1) ? 0 : (k < 6) ? 1 : (k < 15) ? 2 : (k < 28) ? 3 : 4;
}
__device__ __forceinline__ float scale_from_j(int j) {  // sqrt(pi/(4j+1))
  float s = 1.7724539f;
  s = (j == 1) ? 0.79266548f : s;
  s = (j == 2) ? 0.59081795f : s;
  s = (j == 3) ? 0.49159026f : s;
  s = (j >= 4) ? 0.42988324f : s;
  return s;
}
__device__ __forceinline__ float rcp_from_j(int j) {  // 1/scale
  float s = 0.56418958f;
  s = (j == 1) ? 1.2615663f : s;
  s = (j == 2) ? 1.6925688f : s;
  s = (j == 3) ? 2.0342144f : s;
  s = (j >= 4) ? 2.3262120f : s;
  return s;
}
// RNE-adjusted 32-bit word: high 16 bits are the RNE bf16 of v.
__device__ __forceinline__ unsigned rne_adj(float v) {
  const unsigned u = __float_as_uint(v);
  return u + 0x7fffu + ((u >> 16) & 1u);
}
// single-plane RNE store of 4 bf16: 4x rne_adj + 2x v_perm (pk_hi idiom,
// verified r0-r14) + 1 b64 write. Bit-identical to r15's shift/or version.
__device__ __forceinline__ void store4h(unsigned short* dh,
                                        float v0, float v1, float v2, float v3) {
  const unsigned a0 = rne_adj(v0), a1 = rne_adj(v1);
  const unsigned a2 = rne_adj(v2), a3 = rne_adj(v3);
  *(uint2*)dh = make_uint2(__builtin_amdgcn_perm(a1, a0, 0x07060302u),
                           __builtin_amdgcn_perm(a3, a2, 0x07060302u));
}

// ======================= pre-kernel: build fragment dumps =======================
__global__ void scnn_prep(const float* __restrict__ sft, const float* __restrict__ isft,
                          const float* __restrict__ w1, const float* __restrict__ w2,
                          const float* __restrict__ w3, const float* __restrict__ w4,
                          const float* __restrict__ w5, const float* __restrict__ w6,
                          unsigned short* __restrict__ wsu) {
  const int gid = blockIdx.x * NT + threadIdx.x;
  const int gstr = gridDim.x * NT;
  const float* wp[6] = {w1, w2, w3, w4, w5, w6};
  const int CIN[6] = {4, 16, 32, 64, 32, 16};
  const int COUT[6] = {16, 32, 64, 32, 16, 4};
  const int LG[6] = {3, 4, 5, 6, 5, 4};
  const int NST[6] = {2, 3, 5, 10, 5, 3};
  const int NTC[6] = {1, 2, 4, 2, 1, 1};
  const int FOFF[6] = {0, 2, 8, 28, 48, 53};
#pragma unroll
  for (int l = 0; l < 6; ++l) {
    const int cin = CIN[l], cout = COUT[l], lg = LG[l], cinP = 1 << lg;
    const int nst = NST[l];
    const int n = NTC[l] * nst * 512;
    const float* w = wp[l];
    const int base = FOFF[l] * 512;
    for (int i = gid; i < n; i += gstr) {
      const int fid = i >> 9, lane = (i >> 3) & 63, e = i & 7;
      const int nt = fid / nst, st = fid - nt * nst;
      const int o = nt * 16 + (lane & 15);
      const int s = st * 32 + (lane >> 4) * 8 + e;
      const int j = s >> lg, c = s & (cinP - 1);
      float v = 0.f;
      if (o < cout && j < 5 && c < cin) v = w[(o * cin + c) * 5 + j];
      const unsigned short h = f2bf(v);
      wsu[FW_H + base + i] = h;
      wsu[FW_L + base + i] = f2bf(v - bf2f(h));
    }
  }
  for (int i = gid; i < 9 * 512; i += gstr) {  // stage2 32x32 A-frags (isft)
    const int fid = i >> 9, lane = (i >> 3) & 63, e = i & 7;
    const int mt = fid / 3, ks = fid - mt * 3;
    const int p = mt * 32 + (lane & 31);
    const int k = ks * 16 + (lane >> 5) * 8 + e;
    const float v = (p < 90 && k < 45) ? isft[p * 45 + k] : 0.f;
    const unsigned short h = f2bf(v);
    wsu[W2A32_H + i] = h;
    wsu[W2A32_L + i] = f2bf(v - bf2f(h));
  }
  for (int i = gid; i < 9 * 512; i += gstr) {  // stage3 B-frags (scale*sft)
    const int fid = i >> 9, lane = (i >> 3) & 63, e = i & 7;
    const int ntK = fid / 3, sl = fid - ntK * 3;
    const int kk = ntK * 16 + (lane & 15);
    const int p = sl * 32 + (lane >> 4) * 8 + e;
    float v = 0.f;
    if (kk < 45 && p < 90) v = sft[kk * 90 + p] * scale_from_j(lidxf(kk));
    const unsigned short h = f2bf(v);
    wsu[W3B_H + i] = h;
    wsu[W3B_L + i] = f2bf(v - bf2f(h));
  }
}

// stage2 tile: s ~= WI_h · y_h (y single-plane); ks=0 A-frag preloaded. 3-chain.
__device__ __forceinline__ f16v s2tile_pre(const unsigned short* U,
                                           const unsigned short* fh, int nt, int lof,
                                           bh8 pah) {
  f16v a;
#pragma unroll
  for (int e = 0; e < 16; ++e) a[e] = 0.f;
  const unsigned short* yb = U + YHo + nt * 3 * 512 + lof;
  {
    const bh8 bhv = *(const bh8*)&yb[0];
    a = __builtin_amdgcn_mfma_f32_32x32x16_bf16(pah, bhv, a, 0, 0, 0);
  }
#pragma unroll
  for (int ks = 1; ks < 3; ++ks) {
    const bh8 ah = *(const bh8*)&fh[ks * 512];
    const bh8 bhv = *(const bh8*)&yb[ks * 512];
    a = __builtin_amdgcn_mfma_f32_32x32x16_bf16(ah, bhv, a, 0, 0, 0);
  }
  return a;
}
// write s (ReLU'd, RNE bf16 single-plane) into stage-(d) A-frag layout.
__device__ __forceinline__ void writes_s(unsigned short* U, f16v acc, int mt,
                                         int nt, int llo, int lhi) {
  const int so = S2o + ((nt * 2 + (llo >> 4)) * 3 + mt) * 512 + (llo & 15) * 8 + lhi * 4;
#pragma unroll
  for (int g = 0; g < 4; ++g) {
    store4h(&U[so + g * 128],
            fmaxf(acc[g * 4 + 0], 0.f), fmaxf(acc[g * 4 + 1], 0.f),
            fmaxf(acc[g * 4 + 2], 0.f), fmaxf(acc[g * 4 + 3], 0.f));
  }
}

// ---- stage (a) tile: single-plane X, weight-lo dropped -> 1 MFMA + 1 ds_read
// per st iter, single accumulator chain.
template <int layer, int mt>
__device__ __forceinline__ void atile(unsigned short* U,
                                      const unsigned short* __restrict__ wsu,
                                      int nt, int l15, int q4, int lof) {
  constexpr int lg   = (layer == 0) ? 3 : (layer == 1) ? 4 : (layer == 2) ? 5
                     : (layer == 3) ? 6 : (layer == 4) ? 5 : 4;
  constexpr int cinP = 1 << lg;
  constexpr int NSTc = (layer == 0) ? 2 : (layer == 1) ? 3 : (layer == 2) ? 5
                     : (layer == 3) ? 10 : (layer == 4) ? 5 : 3;
  constexpr int FOFFc= (layer == 0) ? 0 : (layer == 1) ? 2 : (layer == 2) ? 8
                     : (layer == 3) ? 28 : (layer == 4) ? 48 : 53;
  constexpr int hi5 = (5 * cinP + 31) >> 5;
  constexpr int hi4 = (4 * cinP + 31) >> 5;
  constexpr int lo3 = (3 * cinP) >> 5;
  constexpr int lo4 = cinP >> 3;
  constexpr int lo = (mt == 0) ? 0 : (mt == 1) ? lo3 : lo4;
  constexpr int hi = (mt == 0) ? hi4 : hi5;
  (void)cinP;

  const int k = mt * 16 + l15;
  const int jb = lidxf(k) << lg;
  const unsigned short* wfh = wsu + FW_H + (FOFFc + nt * NSTc) * 512 + lof;
  f4v a;
  a[0] = a[1] = a[2] = a[3] = 0.f;
#pragma unroll
  for (int st = lo; st < hi; ++st) {
    const int S = st * 32 + q4 * 8;
    const unsigned c0 = (unsigned)(S - jb);
    const unsigned cc = c0 < 64u ? c0 : 64u;  // OOB -> zero pad col
    const bh8 xh = *(const bh8*)&U[XHo + k * 72 + (int)cc];
    const bh8 wh = *(const bh8*)&wfh[st * 512];
    a = __builtin_amdgcn_mfma_f32_16x16x32_bf16(xh, wh, a, 0, 0, 0);
  }
  const int off = (((nt >> 1) * 3 + mt) << 9) +
                  ((q4 >> 1) * 32 + (nt & 1) * 16 + l15) * 8 + (q4 & 1) * 4;
  store4h(&U[YHo + off], a[0], a[1], a[2], a[3]);
}

__device__ __forceinline__ void dstore(unsigned short* U, f4v a, int ntK, int mtO,
                                       int l15, int q4, int layer_zero_mode) {
  const int kk = ntK * 16 + l15;
  const int oc = mtO * 16 + q4 * 4;
  store4h(&U[XHo + kk * 72 + oc], a[0], a[1], a[2], a[3]);
  if (layer_zero_mode == 1) {  // next layer cinP=32: cols 32-63 must be zero
    *(uint2*)&U[XHo + kk * 72 + oc + 32] = make_uint2(0u, 0u);
  }
  if (layer_zero_mode == 2) {  // next layer cinP=16: cols 16-31 must be zero
    *(uint2*)&U[XHo + kk * 72 + oc + 16] = make_uint2(0u, 0u);
  }
}

// ======================= per-layer body =======================
template <int layer>
__device__ __forceinline__ void layer_body(unsigned short* U,
                                           const unsigned short* __restrict__ wsu,
                                           int tid, int wv, int llo, int lhi,
                                           int l15, int q4, int lof) {
  constexpr int nt16 = (layer == 2) ? 4 : (layer == 1 || layer == 3) ? 2 : 1;
  constexpr int n32  = (layer == 2) ? 2 : 1;
  constexpr int zmode = (layer == 3) ? 1 : (layer == 4) ? 2 : 0;

  // ---- (a) sconv via MFMA -> y B-frags (single plane)
  {
    constexpr int T = 3 * nt16;
    for (int t = wv; t < T; t += 8) {
      const int mt = t % 3, nt = t / 3;
      if (mt == 0)      atile<layer, 0>(U, wsu, nt, l15, q4, lof);
      else if (mt == 1) atile<layer, 1>(U, wsu, nt, l15, q4, lof);
      else              atile<layer, 2>(U, wsu, nt, l15, q4, lof);
    }
  }
  // ---- preload stage-b ks=0 A-frag (global, no LDS dep) across barrier
  constexpr int T2 = 3 * n32;
  const bool hA = wv < T2;
  const unsigned short* fh = wsu + W2A32_H + (wv % 3) * 3 * 512 + lof;
  bh8 pah;
  if (hA) pah = *(const bh8*)&fh[0];
  __syncthreads();  // end of stage (a)

  // ---- (b)+(c) stage2 MFMA; y and s regions disjoint -> no mid barrier
  {
    f16v a0;
    if (hA) a0 = s2tile_pre(U, fh, wv / 3, lof, pah);
    if (hA) writes_s(U, a0, wv % 3, wv / 3, llo, lhi);
  }
  // ---- preload stage-d sl=0 B-frag for this group's first ntK
  const int grp = wv >> 2, mtO = wv & 3;
  const bool hD = mtO < nt16;
  const int ntKa = (grp == 0) ? 0 : 2;
  const unsigned short* fba = wsu + W3B_H + ntKa * 3 * 512 + lof;
  bh8 pb;
  if (hD) pb = *(const bh8*)&fba[0];
  __syncthreads();  // end of stage (b)

  // ---- (d) stage3 MFMA: X' ~= s_h · WS_h (all single-plane).
  //      grp0 waves own ntK{0,1} (two accs, shared s reads); grp1 own ntK{2}.
  if (hD) {
    const unsigned short* ab = U + S2o + mtO * 3 * 512 + lof;
    if (grp == 0) {
      const unsigned short* fbb = wsu + W3B_H + 3 * 512 + lof;  // ntK=1
      f4v a0, a1;
      a0[0] = a0[1] = a0[2] = a0[3] = 0.f;
      a1[0] = a1[1] = a1[2] = a1[3] = 0.f;
#pragma unroll
      for (int sl = 0; sl < 3; ++sl) {
        const bh8 ah = *(const bh8*)&ab[sl * 512];
        bh8 b0h;
        if (sl == 0) b0h = pb;
        else         b0h = *(const bh8*)&fba[sl * 512];
        const bh8 b1h = *(const bh8*)&fbb[sl * 512];
        a0 = __builtin_amdgcn_mfma_f32_16x16x32_bf16(ah, b0h, a0, 0, 0, 0);
        a1 = __builtin_amdgcn_mfma_f32_16x16x32_bf16(ah, b1h, a1, 0, 0, 0);
      }
      dstore(U, a0, 0, mtO, l15, q4, zmode);
      dstore(U, a1, 1, mtO, l15, q4, zmode);
    } else {
      f4v a;
      a[0] = a[1] = a[2] = a[3] = 0.f;
#pragma unroll
      for (int sl = 0; sl < 3; ++sl) {
        const bh8 ah = *(const bh8*)&ab[sl * 512];
        bh8 bh_;
        if (sl == 0) bh_ = pb;
        else         bh_ = *(const bh8*)&fba[sl * 512];
        a = __builtin_amdgcn_mfma_f32_16x16x32_bf16(ah, bh_, a, 0, 0, 0);
      }
      dstore(U, a, 2, mtO, l15, q4, zmode);
    }
  }
  __syncthreads();  // end of stage (d)
}

// ======================= main kernel =======================
__global__ __launch_bounds__(NT, 8)
void scnn_main(const float* __restrict__ xin, const unsigned short* __restrict__ wsu,
               float* __restrict__ out) {
  __shared__ __align__(16) unsigned short U[NU];
  const int tid = threadIdx.x, b = blockIdx.x;
  const int lane = tid & 63, wv = tid >> 6;
  const int llo = lane & 31, lhi = lane >> 5;
  const int l15 = lane & 15, q4 = lane >> 4;
  const int lof = lane << 3;

  // ---- zero-fill X region (3456 ush = 864 uint2)
  for (int i = tid; i < 864; i += NT)
    ((uint2*)&U[XHo])[i] = make_uint2(0u, 0u);
  __syncthreads();
  // ---- stage initial X: [k][c] stride 72, live cols 0..3, scale-folded, RNE
  for (int i = tid; i < 180; i += NT) {
    const int c = i / 45, k = i - c * 45;
    const float v = xin[(size_t)b * 180 + i] * scale_from_j(lidxf(k));
    U[XHo + k * 72 + c] = f2bf(v);
  }
  __syncthreads();

  layer_body<0>(U, wsu, tid, wv, llo, lhi, l15, q4, lof);
  layer_body<1>(U, wsu, tid, wv, llo, lhi, l15, q4, lof);
  layer_body<2>(U, wsu, tid, wv, llo, lhi, l15, q4, lof);
  layer_body<3>(U, wsu, tid, wv, llo, lhi, l15, q4, lof);
  layer_body<4>(U, wsu, tid, wv, llo, lhi, l15, q4, lof);
  layer_body<5>(U, wsu, tid, wv, llo, lhi, l15, q4, lof);

  // ---- epilogue: out[b][c][k] = X[k][c] * (1/scale[k])
  for (int i = tid; i < 180; i += NT) {
    const int c = i / 45, k = i - c * 45;
    const float v = bf2f(U[XHo + k * 72 + c]);
    out[(size_t)b * 180 + i] = v * rcp_from_j(lidxf(k));
  }
}

extern "C" void kernel_launch(void* const* d_in, const int* in_sizes, int n_in,
                              void* d_out, int out_size, void* d_ws, size_t ws_size,
                              hipStream_t stream) {
  (void)n_in; (void)out_size; (void)ws_size;
  const float* x    = (const float*)d_in[0];
  const float* sft  = (const float*)d_in[1];
  const float* isft = (const float*)d_in[2];
  const float* w1   = (const float*)d_in[3];
  const float* w2   = (const float*)d_in[4];
  const float* w3   = (const float*)d_in[5];
  const float* w4   = (const float*)d_in[6];
  const float* w5   = (const float*)d_in[7];
  const float* w6   = (const float*)d_in[8];
  float* out = (float*)d_out;
  unsigned short* wsu = (unsigned short*)d_ws;  // uses 151552 B of scratch
  const int nb = in_sizes[0] / 180;             // 50000
  scnn_prep<<<64, NT, 0, stream>>>(sft, isft, w1, w2, w3, w4, w5, w6, wsu);
  scnn_main<<<nb, NT, 0, stream>>>(x, wsu, out);
}

// Round 19
// 611.559 us; speedup vs baseline: 1.6617x; 1.0640x over previous
//
#include <hip/hip_runtime.h>

#define NT 256

typedef __attribute__((ext_vector_type(8)))  short bh8;   // 8 bf16
typedef __attribute__((ext_vector_type(16))) float f16v;  // 32x32 acc
typedef __attribute__((ext_vector_type(4)))  float f4v;   // 16x16 acc

// ---- d_ws layout (ushort units): pre-swizzled 64-lane x 16B fragment dumps.
#define FW_H    0      // sconv expanded-weight B-frags, 56 frags (28672)
#define FW_L    28672
#define W2A32_H 57344  // stage2 32x32 A-frags (isft), 9 frags (4608)
#define W2A32_L 61952
#define W3B_H   66560  // stage3 B-frags (scale*sft), 9 frags (4608)
#define W3B_L   71168  // end 75776 ush = 151552 B

// ---- LDS layout (ushort units) ----
// ALL activations single-plane RNE bf16 (r17-verified): y B-frags, s A-frags,
// X carry [k][c] stride 72 with zero-padded OOB columns.
// 25344 B/block; 4 waves/block -> 6 blocks/CU (152 KB), 24 waves/CU.
#define YHo  0      // y B-frags, up to 6 frags (3072)
#define S2o  3072   // s A-frags, up to 12 frags (6144)
#define XHo  9216   // x plane [k][c] stride 72 (3456)
#define NU   12672

__device__ __forceinline__ unsigned short f2bf(float f) {  // RNE
  unsigned u = __float_as_uint(f);
  return (unsigned short)((u + 0x7fffu + ((u >> 16) & 1u)) >> 16);
}
__device__ __forceinline__ float bf2f(unsigned short h) {
  return __uint_as_float(((unsigned)h) << 16);
}
__device__ __forceinline__ int lidxf(int k) {  // degree band l/2 for coeff k
  return (k < 1) ? 0 : (k < 6) ? 1 : (k < 15) ? 2 : (k < 28) ? 3 : 4;
}
__device__ __forceinline__ float scale_from_j(int j) {  // sqrt(pi/(4j+1))
  float s = 1.7724539f;
  s = (j == 1) ? 0.79266548f : s;
  s = (j == 2) ? 0.59081795f : s;
  s = (j == 3) ? 0.49159026f : s;
  s = (j >= 4) ? 0.42988324f : s;
  return s;
}
__device__ __forceinline__ float rcp_from_j(int j) {  // 1/scale
  float s = 0.56418958f;
  s = (j == 1) ? 1.2615663f : s;
  s = (j == 2) ? 1.6925688f : s;
  s = (j == 3) ? 2.0342144f : s;
  s = (j >= 4) ? 2.3262120f : s;
  return s;
}
// RNE-adjusted 32-bit word: high 16 bits are the RNE bf16 of v.
__device__ __forceinline__ unsigned rne_adj(float v) {
  const unsigned u = __float_as_uint(v);
  return u + 0x7fffu + ((u >> 16) & 1u);
}
// RNE store of 4 bf16: 4x rne_adj + 2x v_perm + 1 b64 write (r17-verified).
__device__ __forceinline__ void store4h(unsigned short* dh,
                                        float v0, float v1, float v2, float v3) {
  const unsigned a0 = rne_adj(v0), a1 = rne_adj(v1);
  const unsigned a2 = rne_adj(v2), a3 = rne_adj(v3);
  *(uint2*)dh = make_uint2(__builtin_amdgcn_perm(a1, a0, 0x07060302u),
                           __builtin_amdgcn_perm(a3, a2, 0x07060302u));
}

// ======================= pre-kernel: build fragment dumps =======================
__global__ void scnn_prep(const float* __restrict__ sft, const float* __restrict__ isft,
                          const float* __restrict__ w1, const float* __restrict__ w2,
                          const float* __restrict__ w3, const float* __restrict__ w4,
                          const float* __restrict__ w5, const float* __restrict__ w6,
                          unsigned short* __restrict__ wsu) {
  const int gid = blockIdx.x * NT + threadIdx.x;
  const int gstr = gridDim.x * NT;
  const float* wp[6] = {w1, w2, w3, w4, w5, w6};
  const int CIN[6] = {4, 16, 32, 64, 32, 16};
  const int COUT[6] = {16, 32, 64, 32, 16, 4};
  const int LG[6] = {3, 4, 5, 6, 5, 4};
  const int NST[6] = {2, 3, 5, 10, 5, 3};
  const int NTC[6] = {1, 2, 4, 2, 1, 1};
  const int FOFF[6] = {0, 2, 8, 28, 48, 53};
#pragma unroll
  for (int l = 0; l < 6; ++l) {
    const int cin = CIN[l], cout = COUT[l], lg = LG[l], cinP = 1 << lg;
    const int nst = NST[l];
    const int n = NTC[l] * nst * 512;
    const float* w = wp[l];
    const int base = FOFF[l] * 512;
    for (int i = gid; i < n; i += gstr) {
      const int fid = i >> 9, lane = (i >> 3) & 63, e = i & 7;
      const int nt = fid / nst, st = fid - nt * nst;
      const int o = nt * 16 + (lane & 15);
      const int s = st * 32 + (lane >> 4) * 8 + e;
      const int j = s >> lg, c = s & (cinP - 1);
      float v = 0.f;
      if (o < cout && j < 5 && c < cin) v = w[(o * cin + c) * 5 + j];
      const unsigned short h = f2bf(v);
      wsu[FW_H + base + i] = h;
      wsu[FW_L + base + i] = f2bf(v - bf2f(h));
    }
  }
  for (int i = gid; i < 9 * 512; i += gstr) {  // stage2 32x32 A-frags (isft)
    const int fid = i >> 9, lane = (i >> 3) & 63, e = i & 7;
    const int mt = fid / 3, ks = fid - mt * 3;
    const int p = mt * 32 + (lane & 31);
    const int k = ks * 16 + (lane >> 5) * 8 + e;
    const float v = (p < 90 && k < 45) ? isft[p * 45 + k] : 0.f;
    const unsigned short h = f2bf(v);
    wsu[W2A32_H + i] = h;
    wsu[W2A32_L + i] = f2bf(v - bf2f(h));
  }
  for (int i = gid; i < 9 * 512; i += gstr) {  // stage3 B-frags (scale*sft)
    const int fid = i >> 9, lane = (i >> 3) & 63, e = i & 7;
    const int ntK = fid / 3, sl = fid - ntK * 3;
    const int kk = ntK * 16 + (lane & 15);
    const int p = sl * 32 + (lane >> 4) * 8 + e;
    float v = 0.f;
    if (kk < 45 && p < 90) v = sft[kk * 90 + p] * scale_from_j(lidxf(kk));
    const unsigned short h = f2bf(v);
    wsu[W3B_H + i] = h;
    wsu[W3B_L + i] = f2bf(v - bf2f(h));
  }
}

// stage2 tile: s ~= WI_h · y_h (y single-plane). 3-chain.
__device__ __forceinline__ f16v s2tile(const unsigned short* U,
                                       const unsigned short* __restrict__ wsu,
                                       int mt, int nt, int lof) {
  f16v a;
#pragma unroll
  for (int e = 0; e < 16; ++e) a[e] = 0.f;
  const unsigned short* fh = wsu + W2A32_H + mt * 3 * 512 + lof;
  const unsigned short* yb = U + YHo + nt * 3 * 512 + lof;
#pragma unroll
  for (int ks = 0; ks < 3; ++ks) {
    const bh8 ah = *(const bh8*)&fh[ks * 512];
    const bh8 bhv = *(const bh8*)&yb[ks * 512];
    a = __builtin_amdgcn_mfma_f32_32x32x16_bf16(ah, bhv, a, 0, 0, 0);
  }
  return a;
}
// write s (ReLU'd, RNE bf16) into stage-(d) A-frag layout.
__device__ __forceinline__ void writes_s(unsigned short* U, f16v acc, int mt,
                                         int nt, int llo, int lhi) {
  const int so = S2o + ((nt * 2 + (llo >> 4)) * 3 + mt) * 512 + (llo & 15) * 8 + lhi * 4;
#pragma unroll
  for (int g = 0; g < 4; ++g) {
    store4h(&U[so + g * 128],
            fmaxf(acc[g * 4 + 0], 0.f), fmaxf(acc[g * 4 + 1], 0.f),
            fmaxf(acc[g * 4 + 2], 0.f), fmaxf(acc[g * 4 + 3], 0.f));
  }
}

// ---- stage (a) tile: single-plane X, 1 MFMA + 1 ds_read per st iter.
template <int layer, int mt>
__device__ __forceinline__ void atile(unsigned short* U,
                                      const unsigned short* __restrict__ wsu,
                                      int nt, int l15, int q4, int lof) {
  constexpr int lg   = (layer == 0) ? 3 : (layer == 1) ? 4 : (layer == 2) ? 5
                     : (layer == 3) ? 6 : (layer == 4) ? 5 : 4;
  constexpr int cinP = 1 << lg;
  constexpr int NSTc = (layer == 0) ? 2 : (layer == 1) ? 3 : (layer == 2) ? 5
                     : (layer == 3) ? 10 : (layer == 4) ? 5 : 3;
  constexpr int FOFFc= (layer == 0) ? 0 : (layer == 1) ? 2 : (layer == 2) ? 8
                     : (layer == 3) ? 28 : (layer == 4) ? 48 : 53;
  constexpr int hi5 = (5 * cinP + 31) >> 5;
  constexpr int hi4 = (4 * cinP + 31) >> 5;
  constexpr int lo3 = (3 * cinP) >> 5;
  constexpr int lo4 = cinP >> 3;
  constexpr int lo = (mt == 0) ? 0 : (mt == 1) ? lo3 : lo4;
  constexpr int hi = (mt == 0) ? hi4 : hi5;
  (void)cinP;

  const int k = mt * 16 + l15;
  const int jb = lidxf(k) << lg;
  const unsigned short* wfh = wsu + FW_H + (FOFFc + nt * NSTc) * 512 + lof;
  f4v a;
  a[0] = a[1] = a[2] = a[3] = 0.f;
#pragma unroll
  for (int st = lo; st < hi; ++st) {
    const int S = st * 32 + q4 * 8;
    const unsigned c0 = (unsigned)(S - jb);
    const unsigned cc = c0 < 64u ? c0 : 64u;  // OOB -> zero pad col
    const bh8 xh = *(const bh8*)&U[XHo + k * 72 + (int)cc];
    const bh8 wh = *(const bh8*)&wfh[st * 512];
    a = __builtin_amdgcn_mfma_f32_16x16x32_bf16(xh, wh, a, 0, 0, 0);
  }
  const int off = (((nt >> 1) * 3 + mt) << 9) +
                  ((q4 >> 1) * 32 + (nt & 1) * 16 + l15) * 8 + (q4 & 1) * 4;
  store4h(&U[YHo + off], a[0], a[1], a[2], a[3]);
}

__device__ __forceinline__ void dstore(unsigned short* U, f4v a, int ntK, int mtO,
                                       int l15, int q4, int layer_zero_mode) {
  const int kk = ntK * 16 + l15;
  const int oc = mtO * 16 + q4 * 4;
  store4h(&U[XHo + kk * 72 + oc], a[0], a[1], a[2], a[3]);  // RNE: X carry
  if (layer_zero_mode == 1) {  // next layer cinP=32: cols 32-63 must be zero
    *(uint2*)&U[XHo + kk * 72 + oc + 32] = make_uint2(0u, 0u);
  }
  if (layer_zero_mode == 2) {  // next layer cinP=16: cols 16-31 must be zero
    *(uint2*)&U[XHo + kk * 72 + oc + 16] = make_uint2(0u, 0u);
  }
}

// ======================= per-layer body (4 waves, stride-4 tile loops) =====
template <int layer>
__device__ __forceinline__ void layer_body(unsigned short* U,
                                           const unsigned short* __restrict__ wsu,
                                           int tid, int wv, int llo, int lhi,
                                           int l15, int q4, int lof) {
  constexpr int nt16 = (layer == 2) ? 4 : (layer == 1 || layer == 3) ? 2 : 1;
  constexpr int n32  = (layer == 2) ? 2 : 1;
  constexpr int zmode = (layer == 3) ? 1 : (layer == 4) ? 2 : 0;

  // ---- (a) sconv via MFMA -> y B-frags (single plane)
  {
    constexpr int T = 3 * nt16;
    for (int t = wv; t < T; t += 4) {
      const int mt = t % 3, nt = t / 3;
      if (mt == 0)      atile<layer, 0>(U, wsu, nt, l15, q4, lof);
      else if (mt == 1) atile<layer, 1>(U, wsu, nt, l15, q4, lof);
      else              atile<layer, 2>(U, wsu, nt, l15, q4, lof);
    }
  }
  __syncthreads();  // end of stage (a)

  // ---- (b)+(c) stage2 MFMA; y and s regions disjoint -> no mid barrier
  {
    constexpr int T2 = 3 * n32;
    for (int t = wv; t < T2; t += 4) {
      const int mt = t % 3, nt = t / 3;
      const f16v a0 = s2tile(U, wsu, mt, nt, lof);
      writes_s(U, a0, mt, nt, llo, lhi);
    }
  }
  __syncthreads();  // end of stage (b)

  // ---- (d) stage3 MFMA: X' ~= s_h · WS_h (all single-plane), simple loop.
  {
    constexpr int T3 = 3 * nt16;
    for (int t = wv; t < T3; t += 4) {
      const int ntK = t % 3, mtO = t / 3;
      const unsigned short* fb = wsu + W3B_H + ntK * 3 * 512 + lof;
      const unsigned short* ab = U + S2o + mtO * 3 * 512 + lof;
      f4v a;
      a[0] = a[1] = a[2] = a[3] = 0.f;
#pragma unroll
      for (int sl = 0; sl < 3; ++sl) {
        const bh8 ah = *(const bh8*)&ab[sl * 512];
        const bh8 bh_ = *(const bh8*)&fb[sl * 512];
        a = __builtin_amdgcn_mfma_f32_16x16x32_bf16(ah, bh_, a, 0, 0, 0);
      }
      dstore(U, a, ntK, mtO, l15, q4, zmode);
    }
  }
  __syncthreads();  // end of stage (d)
}

// ======================= main kernel =======================
__global__ __launch_bounds__(NT, 6)
void scnn_main(const float* __restrict__ xin, const unsigned short* __restrict__ wsu,
               float* __restrict__ out) {
  __shared__ __align__(16) unsigned short U[NU];
  const int tid = threadIdx.x, b = blockIdx.x;
  const int lane = tid & 63, wv = tid >> 6;
  const int llo = lane & 31, lhi = lane >> 5;
  const int l15 = lane & 15, q4 = lane >> 4;
  const int lof = lane << 3;

  // ---- zero-fill X region (3456 ush = 864 uint2)
  for (int i = tid; i < 864; i += NT)
    ((uint2*)&U[XHo])[i] = make_uint2(0u, 0u);
  __syncthreads();
  // ---- stage initial X: [k][c] stride 72, live cols 0..3, scale-folded, RNE
  for (int i = tid; i < 180; i += NT) {
    const int c = i / 45, k = i - c * 45;
    const float v = xin[(size_t)b * 180 + i] * scale_from_j(lidxf(k));
    U[XHo + k * 72 + c] = f2bf(v);
  }
  __syncthreads();

  layer_body<0>(U, wsu, tid, wv, llo, lhi, l15, q4, lof);
  layer_body<1>(U, wsu, tid, wv, llo, lhi, l15, q4, lof);
  layer_body<2>(U, wsu, tid, wv, llo, lhi, l15, q4, lof);
  layer_body<3>(U, wsu, tid, wv, llo, lhi, l15, q4, lof);
  layer_body<4>(U, wsu, tid, wv, llo, lhi, l15, q4, lof);
  layer_body<5>(U, wsu, tid, wv, llo, lhi, l15, q4, lof);

  // ---- epilogue: out[b][c][k] = X[k][c] * (1/scale[k])
  for (int i = tid; i < 180; i += NT) {
    const int c = i / 45, k = i - c * 45;
    const float v = bf2f(U[XHo + k * 72 + c]);
    out[(size_t)b * 180 + i] = v * rcp_from_j(lidxf(k));
  }
}

extern "C" void kernel_launch(void* const* d_in, const int* in_sizes, int n_in,
                              void* d_out, int out_size, void* d_ws, size_t ws_size,
                              hipStream_t stream) {
  (void)n_in; (void)out_size; (void)ws_size;
  const float* x    = (const float*)d_in[0];
  const float* sft  = (const float*)d_in[1];
  const float* isft = (const float*)d_in[2];
  const float* w1   = (const float*)d_in[3];
  const float* w2   = (const float*)d_in[4];
  const float* w3   = (const float*)d_in[5];
  const float* w4   = (const float*)d_in[6];
  const float* w5   = (const float*)d_in[7];
  const float* w6   = (const float*)d_in[8];
  float* out = (float*)d_out;
  unsigned short* wsu = (unsigned short*)d_ws;  // uses 151552 B of scratch
  const int nb = in_sizes[0] / 180;             // 50000
  scnn_prep<<<128, NT, 0, stream>>>(sft, isft, w1, w2, w3, w4, w5, w6, wsu);
  scnn_main<<<nb, NT, 0, stream>>>(x, wsu, out);
}